// Round 9
// baseline (4275.887 us; speedup 1.0000x reference)
//
#include <hip/hip_runtime.h>
#include <hip/hip_bf16.h>

#define NN 80000       // nodes
#define NE 160000      // edges (both directions)
#define HALF 80000
#define HID 300
#define NG 1600

typedef __attribute__((ext_vector_type(8))) short bf16x8v;
typedef __attribute__((ext_vector_type(4))) float f32x4v;

// ---------------- helpers ----------------
__device__ __forceinline__ float bf2f_us(unsigned short u) {
    return __uint_as_float(((unsigned int)u) << 16);
}
__device__ __forceinline__ unsigned short f2bf_us(float f) {
    unsigned int u = __float_as_uint(f);
    u += 0x7fff + ((u >> 16) & 1);   // RNE
    return (unsigned short)(u >> 16);
}
__device__ __forceinline__ float ld1(const float* p) { return *p; }
__device__ __forceinline__ float ld1(const unsigned short* p) { return bf2f_us(*p); }
__device__ __forceinline__ void st1(float* p, float v) { *p = v; }
__device__ __forceinline__ void st1(unsigned short* p, float v) { *p = f2bf_us(v); }
__device__ __forceinline__ float4 ld4(const float* p) { return *(const float4*)p; }
__device__ __forceinline__ float4 ld4(const unsigned short* p) {
    ushort4 u = *(const ushort4*)p;
    return make_float4(bf2f_us(u.x), bf2f_us(u.y), bf2f_us(u.z), bf2f_us(u.w));
}
__device__ __forceinline__ void st4(float* p, float4 v) { *(float4*)p = v; }
__device__ __forceinline__ void st4(unsigned short* p, float4 v) {
    ushort4 u; u.x = f2bf_us(v.x); u.y = f2bf_us(v.y); u.z = f2bf_us(v.z); u.w = f2bf_us(v.w);
    *(ushort4*)p = u;
}
__device__ __forceinline__ int clampi(int v, int lo, int hi) {
    return v < lo ? lo : (v > hi ? hi : v);
}

// ---------------- zero-fill ----------------
__global__ void k_zerof(float* __restrict__ p, int n) {
    int i = blockIdx.x * 256 + threadIdx.x; if (i < n) p[i] = 0.f;
}
__global__ void k_zeroi(int* __restrict__ p, int n) {
    int i = blockIdx.x * 256 + threadIdx.x; if (i < n) p[i] = 0;
}

// ---------------- W split+swizzle: K x 300 fp32 -> hi/lo bf16 fragment order ----------------
// tiles (kt < nkt, ct < 19); lane holds B[k=kt*32+quad*8+j][n=ct*16+(lane&15)], j=0..7
__global__ void k_wsplit_g(const float* __restrict__ W, int Krows, int nkt,
                           unsigned short* __restrict__ whi, unsigned short* __restrict__ wlo) {
    int idx = blockIdx.x * 256 + threadIdx.x;
    if (idx >= nkt * 19 * 64) return;
    int lane = idx & 63;
    int t = idx >> 6;                 // kt*19 + ct
    int kt = t / 19, ct = t - kt * 19;
    int quad = lane >> 4, cr = lane & 15;
    size_t obase = ((size_t)t * 64 + lane) * 8;
    for (int j = 0; j < 8; ++j) {
        int k = kt * 32 + quad * 8 + j;
        int n = ct * 16 + cr;
        float v = (k < Krows && n < 300) ? W[(size_t)k * 300 + n] : 0.f;
        unsigned short hu = f2bf_us(v);
        unsigned short lu = f2bf_us(v - bf2f_us(hu));
        whi[obase + j] = hu;
        wlo[obase + j] = lu;
    }
}

// ---------------- CSR build ----------------
__global__ void k_hist(const int* __restrict__ srcH, const int* __restrict__ dstH, int* __restrict__ deg) {
    int e = blockIdx.x * 256 + threadIdx.x;
    if (e >= NE) return;
    int d = (e < HALF) ? dstH[e] : srcH[e - HALF];
    d = clampi(d, 0, NN - 1);
    atomicAdd(&deg[d], 1);
}
__global__ void k_histg(const int* __restrict__ batch, int* __restrict__ degg) {
    int n = blockIdx.x * 256 + threadIdx.x;
    if (n >= NN) return;
    atomicAdd(&degg[clampi(batch[n], 0, NG - 1)], 1);
}
// alias-safe scan (cursor may alias deg)
__global__ __launch_bounds__(1024) void k_scan_n(const int* __restrict__ deg, int* __restrict__ start,
                                                 int* cursor, int n) {
    __shared__ int part[1024];
    const int t = threadIdx.x;
    const int CH = (n + 1023) / 1024;
    int lo = t * CH;
    int hi = lo + CH; if (hi > n) hi = n;
    int s = 0;
    for (int i = lo; i < hi; ++i) s += deg[i];
    part[t] = s;
    __syncthreads();
    for (int off = 1; off < 1024; off <<= 1) {
        int v = 0;
        if (t >= off) v = part[t - off];
        __syncthreads();
        part[t] += v;
        __syncthreads();
    }
    int run = part[t] - s;
    for (int i = lo; i < hi; ++i) {
        int d = deg[i];
        start[i] = run;
        if (cursor) cursor[i] = run;
        run += d;
    }
    if (t == 1023) start[n] = run;
}
__global__ void k_fill(const int* __restrict__ srcH, const int* __restrict__ dstH,
                       int* __restrict__ cursor, int* __restrict__ elist) {
    int e = blockIdx.x * 256 + threadIdx.x;
    if (e >= NE) return;
    int d = (e < HALF) ? dstH[e] : srcH[e - HALF];
    d = clampi(d, 0, NN - 1);
    int pos = atomicAdd(&cursor[d], 1);
    if (pos >= 0 && pos < NE) elist[pos] = e;
}

// ---------------- segment sum: thread per (node, col-quad), bf16 in/out ----------------
__global__ __launch_bounds__(256) void k_segsum2(const unsigned short* __restrict__ h,
                                                 const int* __restrict__ elist,
                                                 const int* __restrict__ start,
                                                 unsigned short* __restrict__ inc) {
    int t = blockIdx.x * 256 + threadIdx.x;
    if (t >= NN * 75) return;
    int n = t / 75, q = t - n * 75;
    int lo = clampi(start[n], 0, NE), hi = clampi(start[n + 1], 0, NE);
    float4 acc = make_float4(0.f, 0.f, 0.f, 0.f);
    for (int j = lo; j < hi; ++j) {
        int e = clampi(elist[j], 0, NE - 1);
        float4 v = ld4(&h[(size_t)e * 300 + q * 4]);
        acc.x += v.x; acc.y += v.y; acc.z += v.z; acc.w += v.w;
    }
    st4(&inc[(size_t)n * 300 + q * 4], acc);
}

// ---------------- lin GEMM, MFMA (bf16 A-tile, 2 MFMA/tile), 32 rows/block ----------------
// h[e] = relu(concat(node_in[src[e]], ea[e]) @ W + b); LDS-staged contiguous epilogue
template <int NID, typename TN>
__global__ __launch_bounds__(256, 6) void k_lin_mfma(
        const TN* __restrict__ node_in, const float* __restrict__ ea,
        const int* __restrict__ srcH, const int* __restrict__ dstH,
        const unsigned short* __restrict__ whi, const unsigned short* __restrict__ wlo,
        const float* __restrict__ bias, unsigned short* __restrict__ h) {
    constexpr int K = NID + 14;
    constexpr int KP = (K + 31) & ~31;                    // 160 or 320
    constexpr int NKT = KP / 32;
    constexpr int LDK = (KP + 8 < 312) ? 312 : KP + 8;    // >=304 for epilogue reuse; 2-way-safe skew
    __shared__ unsigned short As[32 * LDK];
    __shared__ int ssrc[32];
    const int tid = threadIdx.x;
    const int lane = tid & 63, wv = tid >> 6;
    const int quad = lane >> 4, cr = lane & 15;
    const int e0 = blockIdx.x * 32;
    if (tid < 32) {
        int e = e0 + tid;
        int s = (e < HALF) ? srcH[e] : dstH[e - HALF];
        ssrc[tid] = clampi(s, 0, NN - 1);
    }
    __syncthreads();
    for (int idx = tid; idx < 32 * KP; idx += 256) {
        int r = idx / KP, k = idx - r * KP;
        float v;
        if (k < NID)    v = ld1(&node_in[(size_t)ssrc[r] * NID + k]);
        else if (k < K) v = ea[(size_t)(e0 + r) * 14 + (k - NID)];
        else            v = 0.f;
        As[r * LDK + k] = f2bf_us(v);
    }
    __syncthreads();
    const int rt = wv & 1, c0t = wv >> 1;
    f32x4v acc[10];
    #pragma unroll
    for (int i = 0; i < 10; ++i) {
        int ct = c0t + 2 * i;
        f32x4v a = {0.f, 0.f, 0.f, 0.f};
        if (ct < 19) {
            int col = ct * 16 + cr;
            if (col < 300) { float b = bias[col]; a[0] = b; a[1] = b; a[2] = b; a[3] = b; }
        }
        acc[i] = a;
    }
    for (int kt = 0; kt < NKT; ++kt) {
        bf16x8v a = *(const bf16x8v*)&As[(rt * 16 + cr) * LDK + kt * 32 + quad * 8];
        #pragma unroll
        for (int i = 0; i < 10; ++i) {
            int ct = c0t + 2 * i;
            if (ct >= 19) break;
            size_t base = ((size_t)(kt * 19 + ct) * 64 + lane) * 8;
            bf16x8v bhi = *(const bf16x8v*)&whi[base];
            bf16x8v blo = *(const bf16x8v*)&wlo[base];
            acc[i] = __builtin_amdgcn_mfma_f32_16x16x32_bf16(a, blo, acc[i], 0, 0, 0);
            acc[i] = __builtin_amdgcn_mfma_f32_16x16x32_bf16(a, bhi, acc[i], 0, 0, 0);
        }
    }
    // epilogue: stage into LDS (row-major bf16), then contiguous ushort4 stores
    __syncthreads();
    #pragma unroll
    for (int i = 0; i < 10; ++i) {
        int ct = c0t + 2 * i;
        if (ct >= 19) break;
        int col = ct * 16 + cr;
        if (col >= 300) continue;
        #pragma unroll
        for (int r = 0; r < 4; ++r) {
            int lrow = rt * 16 + quad * 4 + r;
            As[lrow * LDK + col] = f2bf_us(fmaxf(acc[i][r], 0.f));
        }
    }
    __syncthreads();
    for (int idx = tid; idx < 32 * 75; idx += 256) {
        int r = idx / 75, q = idx - r * 75;
        *(ushort4*)&h[(size_t)(e0 + r) * 300 + q * 4] = *(const ushort4*)&As[r * LDK + q * 4];
    }
}

// ---------------- au GEMM, MFMA (bf16 A-tile, 2 MFMA/tile), 16 rows/block ----------------
// out[n] = (relu?)(concat(node_in[n], inc[n]) @ W + b) ; bf16 out, LDS-staged epilogue
template <int NID, typename TN, bool RELU>
__global__ __launch_bounds__(256, 6) void k_au_mfma(
        const TN* __restrict__ node_in, const unsigned short* __restrict__ inc,
        const unsigned short* __restrict__ whi, const unsigned short* __restrict__ wlo,
        const float* __restrict__ bias, unsigned short* __restrict__ out_rows) {
    constexpr int K = NID + 300;
    constexpr int KP = (K + 31) & ~31;     // 448 or 608
    constexpr int NKT = KP / 32;
    constexpr int LDK = KP + 8;            // 456 / 616: >=304, 2-way-safe skew
    __shared__ unsigned short As[16 * LDK];
    const int tid = threadIdx.x;
    const int lane = tid & 63, wv = tid >> 6;
    const int quad = lane >> 4, cr = lane & 15;
    const int n0 = blockIdx.x * 16;
    for (int idx = tid; idx < 16 * KP; idx += 256) {
        int r = idx / KP, k = idx - r * KP;
        int n = n0 + r;
        float v;
        if (k < NID)    v = ld1(&node_in[(size_t)n * NID + k]);
        else if (k < K) v = ld1(&inc[(size_t)n * 300 + (k - NID)]);
        else            v = 0.f;
        As[r * LDK + k] = f2bf_us(v);
    }
    __syncthreads();
    f32x4v acc[5];
    #pragma unroll
    for (int i = 0; i < 5; ++i) {
        int ct = wv + 4 * i;
        f32x4v a = {0.f, 0.f, 0.f, 0.f};
        if (ct < 19) {
            int col = ct * 16 + cr;
            if (col < 300) { float b = bias[col]; a[0] = b; a[1] = b; a[2] = b; a[3] = b; }
        }
        acc[i] = a;
    }
    for (int kt = 0; kt < NKT; ++kt) {
        bf16x8v a = *(const bf16x8v*)&As[cr * LDK + kt * 32 + quad * 8];
        #pragma unroll
        for (int i = 0; i < 5; ++i) {
            int ct = wv + 4 * i;
            if (ct >= 19) break;
            size_t base = ((size_t)(kt * 19 + ct) * 64 + lane) * 8;
            bf16x8v bhi = *(const bf16x8v*)&whi[base];
            bf16x8v blo = *(const bf16x8v*)&wlo[base];
            acc[i] = __builtin_amdgcn_mfma_f32_16x16x32_bf16(a, blo, acc[i], 0, 0, 0);
            acc[i] = __builtin_amdgcn_mfma_f32_16x16x32_bf16(a, bhi, acc[i], 0, 0, 0);
        }
    }
    __syncthreads();
    #pragma unroll
    for (int i = 0; i < 5; ++i) {
        int ct = wv + 4 * i;
        if (ct >= 19) break;
        int col = ct * 16 + cr;
        if (col >= 300) continue;
        #pragma unroll
        for (int r = 0; r < 4; ++r) {
            int lrow = quad * 4 + r;
            float v = acc[i][r];
            As[lrow * LDK + col] = f2bf_us(RELU ? fmaxf(v, 0.f) : v);
        }
    }
    __syncthreads();
    for (int idx = tid; idx < 16 * 75; idx += 256) {
        int r = idx / 75, q = idx - r * 75;
        *(ushort4*)&out_rows[(size_t)(n0 + r) * 300 + q * 4] = *(const ushort4*)&As[r * LDK + q * 4];
    }
}

// ---------------- mp GEMM, MFMA (bf16 A-tile, 2 MFMA/tile) ----------------
// h[e] = relu(h[e] + (inc[src[e]] - h[rev(e)]) @ W + b), 32 rows = 16 pairs / block
__global__ __launch_bounds__(256, 6) void k_mp_mfma(
        unsigned short* __restrict__ h, const unsigned short* __restrict__ inc,
        const int* __restrict__ srcH, const int* __restrict__ dstH,
        const unsigned short* __restrict__ whi, const unsigned short* __restrict__ wlo,
        const float* __restrict__ bias) {
    constexpr int LDK = 328;               // skew 4 banks -> 2-way only; >=304
    __shared__ unsigned short Hs[32 * LDK];
    __shared__ int ssrc[32];
    const int tid = threadIdx.x;
    const int lane = tid & 63;
    const int wv = tid >> 6;
    const int quad = lane >> 4, cr = lane & 15;
    const int p0 = blockIdx.x * 16;
    if (tid < 32) {
        int r = tid;
        int e = (r < 16) ? (p0 + r) : (p0 + r - 16 + HALF);
        int s = (e < HALF) ? srcH[e] : dstH[e - HALF];
        ssrc[r] = clampi(s, 0, NN - 1);
    }
    // stage h_old rows (bf16 direct copy; zero pad cols [300,328))
    for (int idx = tid; idx < 32 * 82; idx += 256) {
        int r = idx / 82, q = idx - r * 82;
        int col = q * 4;
        ushort4 v = make_ushort4(0, 0, 0, 0);
        if (col < 300) {
            int e = (r < 16) ? (p0 + r) : (p0 + r - 16 + HALF);
            v = *(const ushort4*)&h[(size_t)e * 300 + col];
        }
        *(ushort4*)&Hs[r * LDK + col] = v;
    }
    __syncthreads();
    // C init: acc = h_old + bias
    const int rt = wv & 1;
    const int c0t = wv >> 1;
    f32x4v acc[10];
    #pragma unroll
    for (int i = 0; i < 10; ++i) {
        int ct = c0t + 2 * i;
        f32x4v a = {0.f, 0.f, 0.f, 0.f};
        if (ct < 19) {
            int col = ct * 16 + cr;
            if (col < 300) {
                float b = bias[col];
                #pragma unroll
                for (int r = 0; r < 4; ++r)
                    a[r] = bf2f_us(Hs[(rt * 16 + quad * 4 + r) * LDK + col]) + b;
            }
        }
        acc[i] = a;
    }
    __syncthreads();
    // pairwise in-place transform: Hs[r] <- bf16(inc[ssrc[r]] - Hs[r^16])
    for (int idx = tid; idx < 16 * 75; idx += 256) {
        int r = idx / 75, q = idx - r * 75;
        int col = q * 4;
        float4 a = ld4(&Hs[r * LDK + col]);
        float4 b = ld4(&Hs[(r + 16) * LDK + col]);
        float4 i1 = ld4(&inc[(size_t)ssrc[r] * 300 + col]);
        float4 i2 = ld4(&inc[(size_t)ssrc[r + 16] * 300 + col]);
        st4(&Hs[r * LDK + col],        make_float4(i1.x - b.x, i1.y - b.y, i1.z - b.z, i1.w - b.w));
        st4(&Hs[(r + 16) * LDK + col], make_float4(i2.x - a.x, i2.y - a.y, i2.z - a.z, i2.w - a.w));
    }
    __syncthreads();
    for (int kt = 0; kt < 10; ++kt) {
        bf16x8v a = *(const bf16x8v*)&Hs[(rt * 16 + cr) * LDK + kt * 32 + quad * 8];
        #pragma unroll
        for (int i = 0; i < 10; ++i) {
            int ct = c0t + 2 * i;
            if (ct >= 19) break;
            size_t base = ((size_t)(kt * 19 + ct) * 64 + lane) * 8;
            bf16x8v bhi = *(const bf16x8v*)&whi[base];
            bf16x8v blo = *(const bf16x8v*)&wlo[base];
            acc[i] = __builtin_amdgcn_mfma_f32_16x16x32_bf16(a, blo, acc[i], 0, 0, 0);
            acc[i] = __builtin_amdgcn_mfma_f32_16x16x32_bf16(a, bhi, acc[i], 0, 0, 0);
        }
    }
    // epilogue: stage into LDS then contiguous stores (2 contiguous 16-row blocks)
    __syncthreads();
    #pragma unroll
    for (int i = 0; i < 10; ++i) {
        int ct = c0t + 2 * i;
        if (ct >= 19) break;
        int col = ct * 16 + cr;
        if (col >= 300) continue;
        #pragma unroll
        for (int r = 0; r < 4; ++r) {
            int lrow = rt * 16 + quad * 4 + r;
            Hs[lrow * LDK + col] = f2bf_us(fmaxf(acc[i][r], 0.f));
        }
    }
    __syncthreads();
    for (int idx = tid; idx < 32 * 75; idx += 256) {
        int r = idx / 75, q = idx - r * 75;
        int e = (r < 16) ? (p0 + r) : (p0 + r - 16 + HALF);
        *(ushort4*)&h[(size_t)e * 300 + q * 4] = *(const ushort4*)&Hs[r * LDK + q * 4];
    }
}

// ---------------- pooling (bf16 rows) + reparam ----------------
__global__ __launch_bounds__(320) void k_pool(const unsigned short* __restrict__ rows,
                                              const float* __restrict__ wat,
                                              const int* __restrict__ gs, float* __restrict__ outg) {
    int g = blockIdx.x, c = threadIdx.x;
    if (c >= 300) return;
    int lo = clampi(gs[g], 0, NN), hi = clampi(gs[g + 1], 0, NN);
    float acc = 0.f;
    for (int n = lo; n < hi; ++n)
        acc += bf2f_us(rows[(size_t)n * 300 + c]) * wat[n];
    float cn = fmaxf((float)(hi - lo), 1.f);
    outg[g * 300 + c] = acc / cn;
}
__global__ __launch_bounds__(320) void k_final(const float* __restrict__ mu_g, const float* __restrict__ lv_g,
                                               const float* __restrict__ eps, float* __restrict__ out) {
    int g = blockIdx.x, c = threadIdx.x;
    if (c >= 300) return;
    out[g * 300 + c] = mu_g[g * 300 + c] + expf(0.5f * lv_g[g * 300 + c]) * eps[g * 300 + c];
}

extern "C" void kernel_launch(void* const* d_in, const int* in_sizes, int n_in,
                              void* d_out, int out_size, void* d_ws, size_t ws_size,
                              hipStream_t stream) {
    float* outp = (float*)d_out;

    const size_t NEED = 199500000ull;   // exact carve = 199,429,120 B; ws proven >= 200,000,000
    if (ws_size < NEED) {
        k_zerof<<<(out_size + 255) / 256, 256, 0, stream>>>(outp, out_size);
        return;
    }

    const float* x   = (const float*)d_in[0];
    const float* ea  = (const float*)d_in[1];
    const float* wat = (const float*)d_in[2];
    const float* eps = (const float*)d_in[3];
    const int* srcH  = (const int*)d_in[4];
    const int* dstH  = (const int*)d_in[5];
    const int* batch = (const int*)d_in[6];
    const float* w_t_lin  = (const float*)d_in[7];
    const float* b_t_lin  = (const float*)d_in[8];
    const float* w_t_mp   = (const float*)d_in[9];
    const float* b_t_mp   = (const float*)d_in[10];
    const float* w_t_au   = (const float*)d_in[11];
    const float* b_t_au   = (const float*)d_in[12];
    const float* w_mu_lin = (const float*)d_in[13];
    const float* b_mu_lin = (const float*)d_in[14];
    const float* w_mu_mp  = (const float*)d_in[15];
    const float* b_mu_mp  = (const float*)d_in[16];
    const float* w_mu_au  = (const float*)d_in[17];
    const float* b_mu_au  = (const float*)d_in[18];
    const float* w_lv_lin = (const float*)d_in[19];
    const float* b_lv_lin = (const float*)d_in[20];
    const float* w_lv_mp  = (const float*)d_in[21];
    const float* b_lv_mp  = (const float*)d_in[22];
    const float* w_lv_au  = (const float*)d_in[23];
    const float* b_lv_au  = (const float*)d_in[24];

    char* p = (char*)d_ws;
    auto alloc = [&](size_t nbytes) { char* q = p; p += (nbytes + 255) & ~(size_t)255; return q; };
    unsigned short* h   = (unsigned short*)alloc((size_t)NE * 300 * 2);   // 96 MB; tail reused as bf16 rows
    unsigned short* inc = (unsigned short*)alloc((size_t)NN * 300 * 2);   // 48 MB
    unsigned short* sh  = (unsigned short*)alloc((size_t)NN * 300 * 2);   // 48 MB
    const size_t MPU = (size_t)3 * 10 * 19 * 512;   // mp tables: 3 layers x 10kt x 19ct (ushorts)
    unsigned short* wh_mp = (unsigned short*)alloc(MPU * 2);
    unsigned short* wl_mp = (unsigned short*)alloc(MPU * 2);
    const size_t LAU = (size_t)29 * 19 * 512;       // lin+au tables (max 10+19 kt-tiles)
    unsigned short* wh_la = (unsigned short*)alloc(LAU * 2);
    unsigned short* wl_la = (unsigned short*)alloc(LAU * 2);
    float* mu_g = (float*)alloc((size_t)NG * 300 * 4);
    float* lv_g = (float*)alloc((size_t)NG * 300 * 4);
    int* deg    = (int*)alloc(NN * 4);               // reused as cursor (alias-safe)
    int* startA = (int*)alloc((NN + 1) * 4);
    int* elist  = (int*)alloc(NE * 4);
    int* degg   = (int*)alloc(NG * 4);
    int* gs     = (int*)alloc((NG + 1) * 4);

    // ---- CSR (incoming by dst) ----
    k_zeroi<<<(NN + 255) / 256, 256, 0, stream>>>(deg, NN);
    k_hist<<<(NE + 255) / 256, 256, 0, stream>>>(srcH, dstH, deg);
    k_scan_n<<<1, 1024, 0, stream>>>(deg, startA, deg, NN);
    k_fill<<<(NE + 255) / 256, 256, 0, stream>>>(srcH, dstH, deg, elist);
    // ---- graph-CSR over sorted batch ----
    k_zeroi<<<(NG + 255) / 256, 256, 0, stream>>>(degg, NG);
    k_histg<<<(NN + 255) / 256, 256, 0, stream>>>(batch, degg);
    k_scan_n<<<1, 1024, 0, stream>>>(degg, gs, (int*)nullptr, NG);

    const int SSG = (NN * 75 + 255) / 256;
    const size_t MP_L = (size_t)10 * 19 * 512;      // ushorts per mp layer
    unsigned short* rows = h;                        // bf16 rows alias (h dead at that point)
    auto wsplit = [&](const float* W, int K, int nkt, unsigned short* whi, unsigned short* wlo) {
        k_wsplit_g<<<(nkt * 19 * 64 + 255) / 256, 256, 0, stream>>>(W, K, nkt, whi, wlo);
    };

    // ================= conv t =================
    for (int i = 0; i < 3; ++i)
        wsplit(w_t_mp + i * 90000, 300, 10, wh_mp + i * MP_L, wl_mp + i * MP_L);
    wsplit(w_t_lin, 147, 5, wh_la, wl_la);
    const size_t AU_T = (size_t)5 * 19 * 512;
    wsplit(w_t_au, 433, 14, wh_la + AU_T, wl_la + AU_T);
    k_lin_mfma<133, float><<<NE / 32, 256, 0, stream>>>(x, ea, srcH, dstH, wh_la, wl_la, b_t_lin, h);
    for (int i = 0; i < 3; ++i) {
        k_segsum2<<<SSG, 256, 0, stream>>>(h, elist, startA, inc);
        k_mp_mfma<<<HALF / 16, 256, 0, stream>>>(h, inc, srcH, dstH,
                                                 wh_mp + i * MP_L, wl_mp + i * MP_L, b_t_mp + i * 300);
    }
    k_segsum2<<<SSG, 256, 0, stream>>>(h, elist, startA, inc);
    k_au_mfma<133, float, true><<<NN / 16, 256, 0, stream>>>(x, inc, wh_la + AU_T, wl_la + AU_T, b_t_au, sh);

    // ================= conv mu =================
    for (int i = 0; i < 3; ++i)
        wsplit(w_mu_mp + i * 90000, 300, 10, wh_mp + i * MP_L, wl_mp + i * MP_L);
    wsplit(w_mu_lin, 314, 10, wh_la, wl_la);
    const size_t AU_MU = (size_t)10 * 19 * 512;
    wsplit(w_mu_au, 600, 19, wh_la + AU_MU, wl_la + AU_MU);
    k_lin_mfma<300, unsigned short><<<NE / 32, 256, 0, stream>>>(sh, ea, srcH, dstH, wh_la, wl_la, b_mu_lin, h);
    for (int i = 0; i < 3; ++i) {
        k_segsum2<<<SSG, 256, 0, stream>>>(h, elist, startA, inc);
        k_mp_mfma<<<HALF / 16, 256, 0, stream>>>(h, inc, srcH, dstH,
                                                 wh_mp + i * MP_L, wl_mp + i * MP_L, b_mu_mp + i * 300);
    }
    k_segsum2<<<SSG, 256, 0, stream>>>(h, elist, startA, inc);
    k_au_mfma<300, unsigned short, false><<<NN / 16, 256, 0, stream>>>(sh, inc, wh_la + AU_MU, wl_la + AU_MU, b_mu_au, rows);
    k_pool<<<NG, 320, 0, stream>>>(rows, wat, gs, mu_g);

    // ================= conv lv =================
    for (int i = 0; i < 3; ++i)
        wsplit(w_lv_mp + i * 90000, 300, 10, wh_mp + i * MP_L, wl_mp + i * MP_L);
    wsplit(w_lv_lin, 314, 10, wh_la, wl_la);
    wsplit(w_lv_au, 600, 19, wh_la + AU_MU, wl_la + AU_MU);
    k_lin_mfma<300, unsigned short><<<NE / 32, 256, 0, stream>>>(sh, ea, srcH, dstH, wh_la, wl_la, b_lv_lin, h);
    for (int i = 0; i < 3; ++i) {
        k_segsum2<<<SSG, 256, 0, stream>>>(h, elist, startA, inc);
        k_mp_mfma<<<HALF / 16, 256, 0, stream>>>(h, inc, srcH, dstH,
                                                 wh_mp + i * MP_L, wl_mp + i * MP_L, b_lv_mp + i * 300);
    }
    k_segsum2<<<SSG, 256, 0, stream>>>(h, elist, startA, inc);
    k_au_mfma<300, unsigned short, false><<<NN / 16, 256, 0, stream>>>(sh, inc, wh_la + AU_MU, wl_la + AU_MU, b_lv_au, rows);
    k_pool<<<NG, 320, 0, stream>>>(rows, wat, gs, lv_g);

    // ---- reparam ----
    k_final<<<NG, 320, 0, stream>>>(mu_g, lv_g, eps, outp);
}

// Round 10
// 2636.032 us; speedup vs baseline: 1.6221x; 1.6221x over previous
//
#include <hip/hip_runtime.h>
#include <hip/hip_bf16.h>

#define NN 80000       // nodes
#define NE 160000      // edges (both directions)
#define HALF 80000
#define HID 300
#define NG 1600

typedef __attribute__((ext_vector_type(8))) short bf16x8v;
typedef __attribute__((ext_vector_type(4))) float f32x4v;

// ---------------- helpers ----------------
__device__ __forceinline__ float bf2f_us(unsigned short u) {
    return __uint_as_float(((unsigned int)u) << 16);
}
__device__ __forceinline__ unsigned short f2bf_us(float f) {
    unsigned int u = __float_as_uint(f);
    u += 0x7fff + ((u >> 16) & 1);   // RNE
    return (unsigned short)(u >> 16);
}
__device__ __forceinline__ float ld1(const float* p) { return *p; }
__device__ __forceinline__ float ld1(const unsigned short* p) { return bf2f_us(*p); }
__device__ __forceinline__ void st1(float* p, float v) { *p = v; }
__device__ __forceinline__ void st1(unsigned short* p, float v) { *p = f2bf_us(v); }
__device__ __forceinline__ float4 ld4(const float* p) { return *(const float4*)p; }
__device__ __forceinline__ float4 ld4(const unsigned short* p) {
    ushort4 u = *(const ushort4*)p;
    return make_float4(bf2f_us(u.x), bf2f_us(u.y), bf2f_us(u.z), bf2f_us(u.w));
}
__device__ __forceinline__ void st4(float* p, float4 v) { *(float4*)p = v; }
__device__ __forceinline__ void st4(unsigned short* p, float4 v) {
    ushort4 u; u.x = f2bf_us(v.x); u.y = f2bf_us(v.y); u.z = f2bf_us(v.z); u.w = f2bf_us(v.w);
    *(ushort4*)p = u;
}
__device__ __forceinline__ int clampi(int v, int lo, int hi) {
    return v < lo ? lo : (v > hi ? hi : v);
}

// ---------------- zero-fill ----------------
__global__ void k_zerof(float* __restrict__ p, int n) {
    int i = blockIdx.x * 256 + threadIdx.x; if (i < n) p[i] = 0.f;
}
__global__ void k_zeroi(int* __restrict__ p, int n) {
    int i = blockIdx.x * 256 + threadIdx.x; if (i < n) p[i] = 0;
}

// ---------------- W split+swizzle: K x 300 fp32 -> hi/lo bf16 fragment order ----------------
// tiles (kt < nkt, ct < 19); lane holds B[k=kt*32+quad*8+j][n=ct*16+(lane&15)], j=0..7
__global__ void k_wsplit_g(const float* __restrict__ W, int Krows, int nkt,
                           unsigned short* __restrict__ whi, unsigned short* __restrict__ wlo) {
    int idx = blockIdx.x * 256 + threadIdx.x;
    if (idx >= nkt * 19 * 64) return;
    int lane = idx & 63;
    int t = idx >> 6;                 // kt*19 + ct
    int kt = t / 19, ct = t - kt * 19;
    int quad = lane >> 4, cr = lane & 15;
    size_t obase = ((size_t)t * 64 + lane) * 8;
    for (int j = 0; j < 8; ++j) {
        int k = kt * 32 + quad * 8 + j;
        int n = ct * 16 + cr;
        float v = (k < Krows && n < 300) ? W[(size_t)k * 300 + n] : 0.f;
        unsigned short hu = f2bf_us(v);
        unsigned short lu = f2bf_us(v - bf2f_us(hu));
        whi[obase + j] = hu;
        wlo[obase + j] = lu;
    }
}

// ---------------- CSR build ----------------
__global__ void k_hist(const int* __restrict__ srcH, const int* __restrict__ dstH, int* __restrict__ deg) {
    int e = blockIdx.x * 256 + threadIdx.x;
    if (e >= NE) return;
    int d = (e < HALF) ? dstH[e] : srcH[e - HALF];
    d = clampi(d, 0, NN - 1);
    atomicAdd(&deg[d], 1);
}
__global__ void k_histg(const int* __restrict__ batch, int* __restrict__ degg) {
    int n = blockIdx.x * 256 + threadIdx.x;
    if (n >= NN) return;
    atomicAdd(&degg[clampi(batch[n], 0, NG - 1)], 1);
}
// alias-safe scan (cursor may alias deg)
__global__ __launch_bounds__(1024) void k_scan_n(const int* __restrict__ deg, int* __restrict__ start,
                                                 int* cursor, int n) {
    __shared__ int part[1024];
    const int t = threadIdx.x;
    const int CH = (n + 1023) / 1024;
    int lo = t * CH;
    int hi = lo + CH; if (hi > n) hi = n;
    int s = 0;
    for (int i = lo; i < hi; ++i) s += deg[i];
    part[t] = s;
    __syncthreads();
    for (int off = 1; off < 1024; off <<= 1) {
        int v = 0;
        if (t >= off) v = part[t - off];
        __syncthreads();
        part[t] += v;
        __syncthreads();
    }
    int run = part[t] - s;
    for (int i = lo; i < hi; ++i) {
        int d = deg[i];
        start[i] = run;
        if (cursor) cursor[i] = run;
        run += d;
    }
    if (t == 1023) start[n] = run;
}
__global__ void k_fill(const int* __restrict__ srcH, const int* __restrict__ dstH,
                       int* __restrict__ cursor, int* __restrict__ elist) {
    int e = blockIdx.x * 256 + threadIdx.x;
    if (e >= NE) return;
    int d = (e < HALF) ? dstH[e] : srcH[e - HALF];
    d = clampi(d, 0, NN - 1);
    int pos = atomicAdd(&cursor[d], 1);
    if (pos >= 0 && pos < NE) elist[pos] = e;
}

// ---------------- segment sum: thread per (node, col-quad), bf16 in/out ----------------
__global__ __launch_bounds__(256) void k_segsum2(const unsigned short* __restrict__ h,
                                                 const int* __restrict__ elist,
                                                 const int* __restrict__ start,
                                                 unsigned short* __restrict__ inc) {
    int t = blockIdx.x * 256 + threadIdx.x;
    if (t >= NN * 75) return;
    int n = t / 75, q = t - n * 75;
    int lo = clampi(start[n], 0, NE), hi = clampi(start[n + 1], 0, NE);
    float4 acc = make_float4(0.f, 0.f, 0.f, 0.f);
    for (int j = lo; j < hi; ++j) {
        int e = clampi(elist[j], 0, NE - 1);
        float4 v = ld4(&h[(size_t)e * 300 + q * 4]);
        acc.x += v.x; acc.y += v.y; acc.z += v.z; acc.w += v.w;
    }
    st4(&inc[(size_t)n * 300 + q * 4], acc);
}

// ================= GEMM core note =================
// 512 threads = 8 waves; M-tile = 64 rows; wave w owns ct = w + 8c (c<3, ct<19).
// Per kt: wave loads its <=3 B hi/lo tile pairs into VGPRs ONCE, then loops 4
// row-sub-tiles (rt) reusing them -> B L2 traffic multiplicity 1 (was 2-38).

// ---------------- lin GEMM v2: h[e] = relu(concat(node_in[src[e]], ea[e]) @ W + b) ----------------
template <int NID, typename TN>
__global__ __launch_bounds__(512, 4) void k_lin_mfma(
        const TN* __restrict__ node_in, const float* __restrict__ ea,
        const int* __restrict__ srcH, const int* __restrict__ dstH,
        const unsigned short* __restrict__ whi, const unsigned short* __restrict__ wlo,
        const float* __restrict__ bias, unsigned short* __restrict__ h) {
    constexpr int K = NID + 14;
    constexpr int KP = (K + 31) & ~31;                    // 160 or 320
    constexpr int NKT = KP / 32;
    constexpr int LDK = (KP + 8 < 312) ? 312 : KP + 8;    // >=304 for epilogue; 2-way-safe skew
    __shared__ unsigned short As[64 * LDK];
    __shared__ int ssrc[64];
    const int tid = threadIdx.x;
    const int lane = tid & 63, wv = tid >> 6;
    const int quad = lane >> 4, cr = lane & 15;
    const int e0 = blockIdx.x * 64;
    if (tid < 64) {
        int e = e0 + tid;
        int s = (e < HALF) ? srcH[e] : dstH[e - HALF];
        ssrc[tid] = clampi(s, 0, NN - 1);
    }
    __syncthreads();
    for (int idx = tid; idx < 64 * KP; idx += 512) {
        int r = idx / KP, k = idx - r * KP;
        float v;
        if (k < NID)    v = ld1(&node_in[(size_t)ssrc[r] * NID + k]);
        else if (k < K) v = ea[(size_t)(e0 + r) * 14 + (k - NID)];
        else            v = 0.f;
        As[r * LDK + k] = f2bf_us(v);
    }
    __syncthreads();
    f32x4v acc[4][3];
    #pragma unroll
    for (int c = 0; c < 3; ++c) {
        int ct = wv + 8 * c;
        float b = 0.f;
        if (ct < 19) { int col = ct * 16 + cr; if (col < 300) b = bias[col]; }
        #pragma unroll
        for (int rt = 0; rt < 4; ++rt) { f32x4v a = {b, b, b, b}; acc[rt][c] = a; }
    }
    for (int kt = 0; kt < NKT; ++kt) {
        bf16x8v bhi[3], blo[3];
        #pragma unroll
        for (int c = 0; c < 3; ++c) {
            int ct = wv + 8 * c;
            if (ct < 19) {
                size_t base = ((size_t)(kt * 19 + ct) * 64 + lane) * 8;
                bhi[c] = *(const bf16x8v*)&whi[base];
                blo[c] = *(const bf16x8v*)&wlo[base];
            }
        }
        #pragma unroll
        for (int rt = 0; rt < 4; ++rt) {
            bf16x8v a = *(const bf16x8v*)&As[(rt * 16 + cr) * LDK + kt * 32 + quad * 8];
            #pragma unroll
            for (int c = 0; c < 3; ++c) {
                int ct = wv + 8 * c;
                if (ct >= 19) break;
                acc[rt][c] = __builtin_amdgcn_mfma_f32_16x16x32_bf16(a, blo[c], acc[rt][c], 0, 0, 0);
                acc[rt][c] = __builtin_amdgcn_mfma_f32_16x16x32_bf16(a, bhi[c], acc[rt][c], 0, 0, 0);
            }
        }
    }
    __syncthreads();
    #pragma unroll
    for (int c = 0; c < 3; ++c) {
        int ct = wv + 8 * c;
        if (ct >= 19) break;
        int col = ct * 16 + cr;
        if (col >= 300) continue;
        #pragma unroll
        for (int rt = 0; rt < 4; ++rt)
            #pragma unroll
            for (int r = 0; r < 4; ++r)
                As[(rt * 16 + quad * 4 + r) * LDK + col] = f2bf_us(fmaxf(acc[rt][c][r], 0.f));
    }
    __syncthreads();
    for (int idx = tid; idx < 64 * 75; idx += 512) {
        int r = idx / 75, q = idx - r * 75;
        *(ushort4*)&h[(size_t)(e0 + r) * 300 + q * 4] = *(const ushort4*)&As[r * LDK + q * 4];
    }
}

// ---------------- au GEMM v2: out[n] = (relu?)(concat(node_in[n], inc[n]) @ W + b) ----------------
template <int NID, typename TN, bool RELU>
__global__ __launch_bounds__(512, 4) void k_au_mfma(
        const TN* __restrict__ node_in, const unsigned short* __restrict__ inc,
        const unsigned short* __restrict__ whi, const unsigned short* __restrict__ wlo,
        const float* __restrict__ bias, unsigned short* __restrict__ out_rows) {
    constexpr int K = NID + 300;
    constexpr int KP = (K + 31) & ~31;     // 448 or 608
    constexpr int NKT = KP / 32;
    constexpr int LDK = KP + 8;            // 456 / 616
    __shared__ unsigned short As[64 * LDK];
    const int tid = threadIdx.x;
    const int lane = tid & 63, wv = tid >> 6;
    const int quad = lane >> 4, cr = lane & 15;
    const int n0 = blockIdx.x * 64;
    for (int idx = tid; idx < 64 * KP; idx += 512) {
        int r = idx / KP, k = idx - r * KP;
        int n = n0 + r;
        float v;
        if (k < NID)    v = ld1(&node_in[(size_t)n * NID + k]);
        else if (k < K) v = ld1(&inc[(size_t)n * 300 + (k - NID)]);
        else            v = 0.f;
        As[r * LDK + k] = f2bf_us(v);
    }
    __syncthreads();
    f32x4v acc[4][3];
    #pragma unroll
    for (int c = 0; c < 3; ++c) {
        int ct = wv + 8 * c;
        float b = 0.f;
        if (ct < 19) { int col = ct * 16 + cr; if (col < 300) b = bias[col]; }
        #pragma unroll
        for (int rt = 0; rt < 4; ++rt) { f32x4v a = {b, b, b, b}; acc[rt][c] = a; }
    }
    for (int kt = 0; kt < NKT; ++kt) {
        bf16x8v bhi[3], blo[3];
        #pragma unroll
        for (int c = 0; c < 3; ++c) {
            int ct = wv + 8 * c;
            if (ct < 19) {
                size_t base = ((size_t)(kt * 19 + ct) * 64 + lane) * 8;
                bhi[c] = *(const bf16x8v*)&whi[base];
                blo[c] = *(const bf16x8v*)&wlo[base];
            }
        }
        #pragma unroll
        for (int rt = 0; rt < 4; ++rt) {
            bf16x8v a = *(const bf16x8v*)&As[(rt * 16 + cr) * LDK + kt * 32 + quad * 8];
            #pragma unroll
            for (int c = 0; c < 3; ++c) {
                int ct = wv + 8 * c;
                if (ct >= 19) break;
                acc[rt][c] = __builtin_amdgcn_mfma_f32_16x16x32_bf16(a, blo[c], acc[rt][c], 0, 0, 0);
                acc[rt][c] = __builtin_amdgcn_mfma_f32_16x16x32_bf16(a, bhi[c], acc[rt][c], 0, 0, 0);
            }
        }
    }
    __syncthreads();
    #pragma unroll
    for (int c = 0; c < 3; ++c) {
        int ct = wv + 8 * c;
        if (ct >= 19) break;
        int col = ct * 16 + cr;
        if (col >= 300) continue;
        #pragma unroll
        for (int rt = 0; rt < 4; ++rt)
            #pragma unroll
            for (int r = 0; r < 4; ++r) {
                float v = acc[rt][c][r];
                As[(rt * 16 + quad * 4 + r) * LDK + col] = f2bf_us(RELU ? fmaxf(v, 0.f) : v);
            }
    }
    __syncthreads();
    for (int idx = tid; idx < 64 * 75; idx += 512) {
        int r = idx / 75, q = idx - r * 75;
        *(ushort4*)&out_rows[(size_t)(n0 + r) * 300 + q * 4] = *(const ushort4*)&As[r * LDK + q * 4];
    }
}

// ---------------- mp GEMM v2: h[e] = relu(h[e] + (inc[src[e]] - h[rev(e)]) @ W + b) ----------------
// 64 rows = 32 pairs / block (pair r <-> r+32)
__global__ __launch_bounds__(512, 4) void k_mp_mfma(
        unsigned short* __restrict__ h, const unsigned short* __restrict__ inc,
        const int* __restrict__ srcH, const int* __restrict__ dstH,
        const unsigned short* __restrict__ whi, const unsigned short* __restrict__ wlo,
        const float* __restrict__ bias) {
    constexpr int LDK = 328;
    __shared__ unsigned short Hs[64 * LDK];
    __shared__ int ssrc[64];
    const int tid = threadIdx.x;
    const int lane = tid & 63, wv = tid >> 6;
    const int quad = lane >> 4, cr = lane & 15;
    const int p0 = blockIdx.x * 32;
    if (tid < 64) {
        int r = tid;
        int e = (r < 32) ? (p0 + r) : (p0 + r - 32 + HALF);
        int s = (e < HALF) ? srcH[e] : dstH[e - HALF];
        ssrc[r] = clampi(s, 0, NN - 1);
    }
    // stage h_old rows (bf16 copy; zero pad cols [300,328))
    for (int idx = tid; idx < 64 * 82; idx += 512) {
        int r = idx / 82, q = idx - r * 82;
        int col = q * 4;
        ushort4 v = make_ushort4(0, 0, 0, 0);
        if (col < 300) {
            int e = (r < 32) ? (p0 + r) : (p0 + r - 32 + HALF);
            v = *(const ushort4*)&h[(size_t)e * 300 + col];
        }
        *(ushort4*)&Hs[r * LDK + col] = v;
    }
    __syncthreads();
    // C init: acc = h_old + bias
    f32x4v acc[4][3];
    #pragma unroll
    for (int c = 0; c < 3; ++c) {
        int ct = wv + 8 * c;
        int col = ct * 16 + cr;
        bool ok = (ct < 19) && (col < 300);
        float b = ok ? bias[col] : 0.f;
        #pragma unroll
        for (int rt = 0; rt < 4; ++rt) {
            f32x4v a = {0.f, 0.f, 0.f, 0.f};
            if (ok) {
                #pragma unroll
                for (int r = 0; r < 4; ++r)
                    a[r] = bf2f_us(Hs[(rt * 16 + quad * 4 + r) * LDK + col]) + b;
            }
            acc[rt][c] = a;
        }
    }
    __syncthreads();
    // pairwise in-place transform: Hs[r] <- bf16(inc[ssrc[r]] - Hs[r^32])
    for (int idx = tid; idx < 32 * 75; idx += 512) {
        int r = idx / 75, q = idx - r * 75;
        int col = q * 4;
        float4 a = ld4(&Hs[r * LDK + col]);
        float4 b = ld4(&Hs[(r + 32) * LDK + col]);
        float4 i1 = ld4(&inc[(size_t)ssrc[r] * 300 + col]);
        float4 i2 = ld4(&inc[(size_t)ssrc[r + 32] * 300 + col]);
        st4(&Hs[r * LDK + col],        make_float4(i1.x - b.x, i1.y - b.y, i1.z - b.z, i1.w - b.w));
        st4(&Hs[(r + 32) * LDK + col], make_float4(i2.x - a.x, i2.y - a.y, i2.z - a.z, i2.w - a.w));
    }
    __syncthreads();
    for (int kt = 0; kt < 10; ++kt) {
        bf16x8v bhi[3], blo[3];
        #pragma unroll
        for (int c = 0; c < 3; ++c) {
            int ct = wv + 8 * c;
            if (ct < 19) {
                size_t base = ((size_t)(kt * 19 + ct) * 64 + lane) * 8;
                bhi[c] = *(const bf16x8v*)&whi[base];
                blo[c] = *(const bf16x8v*)&wlo[base];
            }
        }
        #pragma unroll
        for (int rt = 0; rt < 4; ++rt) {
            bf16x8v a = *(const bf16x8v*)&Hs[(rt * 16 + cr) * LDK + kt * 32 + quad * 8];
            #pragma unroll
            for (int c = 0; c < 3; ++c) {
                int ct = wv + 8 * c;
                if (ct >= 19) break;
                acc[rt][c] = __builtin_amdgcn_mfma_f32_16x16x32_bf16(a, blo[c], acc[rt][c], 0, 0, 0);
                acc[rt][c] = __builtin_amdgcn_mfma_f32_16x16x32_bf16(a, bhi[c], acc[rt][c], 0, 0, 0);
            }
        }
    }
    __syncthreads();
    #pragma unroll
    for (int c = 0; c < 3; ++c) {
        int ct = wv + 8 * c;
        if (ct >= 19) break;
        int col = ct * 16 + cr;
        if (col >= 300) continue;
        #pragma unroll
        for (int rt = 0; rt < 4; ++rt)
            #pragma unroll
            for (int r = 0; r < 4; ++r)
                Hs[(rt * 16 + quad * 4 + r) * LDK + col] = f2bf_us(fmaxf(acc[rt][c][r], 0.f));
    }
    __syncthreads();
    for (int idx = tid; idx < 64 * 75; idx += 512) {
        int r = idx / 75, q = idx - r * 75;
        int e = (r < 32) ? (p0 + r) : (p0 + r - 32 + HALF);
        *(ushort4*)&h[(size_t)e * 300 + q * 4] = *(const ushort4*)&Hs[r * LDK + q * 4];
    }
}

// ---------------- pooling (bf16 rows) + reparam ----------------
__global__ __launch_bounds__(320) void k_pool(const unsigned short* __restrict__ rows,
                                              const float* __restrict__ wat,
                                              const int* __restrict__ gs, float* __restrict__ outg) {
    int g = blockIdx.x, c = threadIdx.x;
    if (c >= 300) return;
    int lo = clampi(gs[g], 0, NN), hi = clampi(gs[g + 1], 0, NN);
    float acc = 0.f;
    for (int n = lo; n < hi; ++n)
        acc += bf2f_us(rows[(size_t)n * 300 + c]) * wat[n];
    float cn = fmaxf((float)(hi - lo), 1.f);
    outg[g * 300 + c] = acc / cn;
}
__global__ __launch_bounds__(320) void k_final(const float* __restrict__ mu_g, const float* __restrict__ lv_g,
                                               const float* __restrict__ eps, float* __restrict__ out) {
    int g = blockIdx.x, c = threadIdx.x;
    if (c >= 300) return;
    out[g * 300 + c] = mu_g[g * 300 + c] + expf(0.5f * lv_g[g * 300 + c]) * eps[g * 300 + c];
}

extern "C" void kernel_launch(void* const* d_in, const int* in_sizes, int n_in,
                              void* d_out, int out_size, void* d_ws, size_t ws_size,
                              hipStream_t stream) {
    float* outp = (float*)d_out;

    const size_t NEED = 199500000ull;   // exact carve = 199,429,120 B; ws proven >= 200,000,000
    if (ws_size < NEED) {
        k_zerof<<<(out_size + 255) / 256, 256, 0, stream>>>(outp, out_size);
        return;
    }

    const float* x   = (const float*)d_in[0];
    const float* ea  = (const float*)d_in[1];
    const float* wat = (const float*)d_in[2];
    const float* eps = (const float*)d_in[3];
    const int* srcH  = (const int*)d_in[4];
    const int* dstH  = (const int*)d_in[5];
    const int* batch = (const int*)d_in[6];
    const float* w_t_lin  = (const float*)d_in[7];
    const float* b_t_lin  = (const float*)d_in[8];
    const float* w_t_mp   = (const float*)d_in[9];
    const float* b_t_mp   = (const float*)d_in[10];
    const float* w_t_au   = (const float*)d_in[11];
    const float* b_t_au   = (const float*)d_in[12];
    const float* w_mu_lin = (const float*)d_in[13];
    const float* b_mu_lin = (const float*)d_in[14];
    const float* w_mu_mp  = (const float*)d_in[15];
    const float* b_mu_mp  = (const float*)d_in[16];
    const float* w_mu_au  = (const float*)d_in[17];
    const float* b_mu_au  = (const float*)d_in[18];
    const float* w_lv_lin = (const float*)d_in[19];
    const float* b_lv_lin = (const float*)d_in[20];
    const float* w_lv_mp  = (const float*)d_in[21];
    const float* b_lv_mp  = (const float*)d_in[22];
    const float* w_lv_au  = (const float*)d_in[23];
    const float* b_lv_au  = (const float*)d_in[24];

    char* p = (char*)d_ws;
    auto alloc = [&](size_t nbytes) { char* q = p; p += (nbytes + 255) & ~(size_t)255; return q; };
    unsigned short* h   = (unsigned short*)alloc((size_t)NE * 300 * 2);   // 96 MB; tail reused as bf16 rows
    unsigned short* inc = (unsigned short*)alloc((size_t)NN * 300 * 2);   // 48 MB
    unsigned short* sh  = (unsigned short*)alloc((size_t)NN * 300 * 2);   // 48 MB
    const size_t MPU = (size_t)3 * 10 * 19 * 512;   // mp tables: 3 layers x 10kt x 19ct (ushorts)
    unsigned short* wh_mp = (unsigned short*)alloc(MPU * 2);
    unsigned short* wl_mp = (unsigned short*)alloc(MPU * 2);
    const size_t LAU = (size_t)29 * 19 * 512;       // lin+au tables (max 10+19 kt-tiles)
    unsigned short* wh_la = (unsigned short*)alloc(LAU * 2);
    unsigned short* wl_la = (unsigned short*)alloc(LAU * 2);
    float* mu_g = (float*)alloc((size_t)NG * 300 * 4);
    float* lv_g = (float*)alloc((size_t)NG * 300 * 4);
    int* deg    = (int*)alloc(NN * 4);               // reused as cursor (alias-safe)
    int* startA = (int*)alloc((NN + 1) * 4);
    int* elist  = (int*)alloc(NE * 4);
    int* degg   = (int*)alloc(NG * 4);
    int* gs     = (int*)alloc((NG + 1) * 4);

    // ---- CSR (incoming by dst) ----
    k_zeroi<<<(NN + 255) / 256, 256, 0, stream>>>(deg, NN);
    k_hist<<<(NE + 255) / 256, 256, 0, stream>>>(srcH, dstH, deg);
    k_scan_n<<<1, 1024, 0, stream>>>(deg, startA, deg, NN);
    k_fill<<<(NE + 255) / 256, 256, 0, stream>>>(srcH, dstH, deg, elist);
    // ---- graph-CSR over sorted batch ----
    k_zeroi<<<(NG + 255) / 256, 256, 0, stream>>>(degg, NG);
    k_histg<<<(NN + 255) / 256, 256, 0, stream>>>(batch, degg);
    k_scan_n<<<1, 1024, 0, stream>>>(degg, gs, (int*)nullptr, NG);

    const int SSG = (NN * 75 + 255) / 256;
    const size_t MP_L = (size_t)10 * 19 * 512;      // ushorts per mp layer
    unsigned short* rows = h;                        // bf16 rows alias (h dead at that point)
    auto wsplit = [&](const float* W, int K, int nkt, unsigned short* whi, unsigned short* wlo) {
        k_wsplit_g<<<(nkt * 19 * 64 + 255) / 256, 256, 0, stream>>>(W, K, nkt, whi, wlo);
    };

    // ================= conv t =================
    for (int i = 0; i < 3; ++i)
        wsplit(w_t_mp + i * 90000, 300, 10, wh_mp + i * MP_L, wl_mp + i * MP_L);
    wsplit(w_t_lin, 147, 5, wh_la, wl_la);
    const size_t AU_T = (size_t)5 * 19 * 512;
    wsplit(w_t_au, 433, 14, wh_la + AU_T, wl_la + AU_T);
    k_lin_mfma<133, float><<<NE / 64, 512, 0, stream>>>(x, ea, srcH, dstH, wh_la, wl_la, b_t_lin, h);
    for (int i = 0; i < 3; ++i) {
        k_segsum2<<<SSG, 256, 0, stream>>>(h, elist, startA, inc);
        k_mp_mfma<<<HALF / 32, 512, 0, stream>>>(h, inc, srcH, dstH,
                                                 wh_mp + i * MP_L, wl_mp + i * MP_L, b_t_mp + i * 300);
    }
    k_segsum2<<<SSG, 256, 0, stream>>>(h, elist, startA, inc);
    k_au_mfma<133, float, true><<<NN / 64, 512, 0, stream>>>(x, inc, wh_la + AU_T, wl_la + AU_T, b_t_au, sh);

    // ================= conv mu =================
    for (int i = 0; i < 3; ++i)
        wsplit(w_mu_mp + i * 90000, 300, 10, wh_mp + i * MP_L, wl_mp + i * MP_L);
    wsplit(w_mu_lin, 314, 10, wh_la, wl_la);
    const size_t AU_MU = (size_t)10 * 19 * 512;
    wsplit(w_mu_au, 600, 19, wh_la + AU_MU, wl_la + AU_MU);
    k_lin_mfma<300, unsigned short><<<NE / 64, 512, 0, stream>>>(sh, ea, srcH, dstH, wh_la, wl_la, b_mu_lin, h);
    for (int i = 0; i < 3; ++i) {
        k_segsum2<<<SSG, 256, 0, stream>>>(h, elist, startA, inc);
        k_mp_mfma<<<HALF / 32, 512, 0, stream>>>(h, inc, srcH, dstH,
                                                 wh_mp + i * MP_L, wl_mp + i * MP_L, b_mu_mp + i * 300);
    }
    k_segsum2<<<SSG, 256, 0, stream>>>(h, elist, startA, inc);
    k_au_mfma<300, unsigned short, false><<<NN / 64, 512, 0, stream>>>(sh, inc, wh_la + AU_MU, wl_la + AU_MU, b_mu_au, rows);
    k_pool<<<NG, 320, 0, stream>>>(rows, wat, gs, mu_g);

    // ================= conv lv =================
    for (int i = 0; i < 3; ++i)
        wsplit(w_lv_mp + i * 90000, 300, 10, wh_mp + i * MP_L, wl_mp + i * MP_L);
    wsplit(w_lv_lin, 314, 10, wh_la, wl_la);
    wsplit(w_lv_au, 600, 19, wh_la + AU_MU, wl_la + AU_MU);
    k_lin_mfma<300, unsigned short><<<NE / 64, 512, 0, stream>>>(sh, ea, srcH, dstH, wh_la, wl_la, b_lv_lin, h);
    for (int i = 0; i < 3; ++i) {
        k_segsum2<<<SSG, 256, 0, stream>>>(h, elist, startA, inc);
        k_mp_mfma<<<HALF / 32, 512, 0, stream>>>(h, inc, srcH, dstH,
                                                 wh_mp + i * MP_L, wl_mp + i * MP_L, b_lv_mp + i * 300);
    }
    k_segsum2<<<SSG, 256, 0, stream>>>(h, elist, startA, inc);
    k_au_mfma<300, unsigned short, false><<<NN / 64, 512, 0, stream>>>(sh, inc, wh_la + AU_MU, wl_la + AU_MU, b_lv_au, rows);
    k_pool<<<NG, 320, 0, stream>>>(rows, wat, gs, lv_g);

    // ---- reparam ----
    k_final<<<NG, 320, 0, stream>>>(mu_g, lv_g, eps, outp);
}

// Round 11
// 2463.236 us; speedup vs baseline: 1.7359x; 1.0701x over previous
//
#include <hip/hip_runtime.h>
#include <hip/hip_bf16.h>

#define NN 80000       // nodes
#define NE 160000      // edges (both directions)
#define HALF 80000
#define HID 300
#define NG 1600
#define SCB 256        // scan blocks

typedef __attribute__((ext_vector_type(8))) short bf16x8v;
typedef __attribute__((ext_vector_type(4))) float f32x4v;

// ---------------- helpers ----------------
__device__ __forceinline__ float bf2f_us(unsigned short u) {
    return __uint_as_float(((unsigned int)u) << 16);
}
__device__ __forceinline__ unsigned short f2bf_us(float f) {
    unsigned int u = __float_as_uint(f);
    u += 0x7fff + ((u >> 16) & 1);   // RNE
    return (unsigned short)(u >> 16);
}
__device__ __forceinline__ float ld1(const float* p) { return *p; }
__device__ __forceinline__ float ld1(const unsigned short* p) { return bf2f_us(*p); }
__device__ __forceinline__ void st1(float* p, float v) { *p = v; }
__device__ __forceinline__ void st1(unsigned short* p, float v) { *p = f2bf_us(v); }
__device__ __forceinline__ float4 ld4(const float* p) { return *(const float4*)p; }
__device__ __forceinline__ float4 ld4(const unsigned short* p) {
    ushort4 u = *(const ushort4*)p;
    return make_float4(bf2f_us(u.x), bf2f_us(u.y), bf2f_us(u.z), bf2f_us(u.w));
}
__device__ __forceinline__ void st4(float* p, float4 v) { *(float4*)p = v; }
__device__ __forceinline__ void st4(unsigned short* p, float4 v) {
    ushort4 u; u.x = f2bf_us(v.x); u.y = f2bf_us(v.y); u.z = f2bf_us(v.z); u.w = f2bf_us(v.w);
    *(ushort4*)p = u;
}
__device__ __forceinline__ int clampi(int v, int lo, int hi) {
    return v < lo ? lo : (v > hi ? hi : v);
}

// ---------------- zero-fill ----------------
__global__ void k_zerof(float* __restrict__ p, int n) {
    int i = blockIdx.x * 256 + threadIdx.x; if (i < n) p[i] = 0.f;
}
__global__ void k_zeroi(int* __restrict__ p, int n) {
    int i = blockIdx.x * 256 + threadIdx.x; if (i < n) p[i] = 0;
}

// ---------------- W split+swizzle: K x 300 fp32 -> hi/lo bf16 fragment order ----------------
__global__ void k_wsplit_g(const float* __restrict__ W, int Krows, int nkt,
                           unsigned short* __restrict__ whi, unsigned short* __restrict__ wlo) {
    int idx = blockIdx.x * 256 + threadIdx.x;
    if (idx >= nkt * 19 * 64) return;
    int lane = idx & 63;
    int t = idx >> 6;                 // kt*19 + ct
    int kt = t / 19, ct = t - kt * 19;
    int quad = lane >> 4, cr = lane & 15;
    size_t obase = ((size_t)t * 64 + lane) * 8;
    for (int j = 0; j < 8; ++j) {
        int k = kt * 32 + quad * 8 + j;
        int n = ct * 16 + cr;
        float v = (k < Krows && n < 300) ? W[(size_t)k * 300 + n] : 0.f;
        unsigned short hu = f2bf_us(v);
        unsigned short lu = f2bf_us(v - bf2f_us(hu));
        whi[obase + j] = hu;
        wlo[obase + j] = lu;
    }
}

// ---------------- CSR build ----------------
__global__ void k_hist(const int* __restrict__ srcH, const int* __restrict__ dstH, int* __restrict__ deg) {
    int e = blockIdx.x * 256 + threadIdx.x;
    if (e >= NE) return;
    int d = (e < HALF) ? dstH[e] : srcH[e - HALF];
    d = clampi(d, 0, NN - 1);
    atomicAdd(&deg[d], 1);
}
__global__ void k_histg(const int* __restrict__ batch, int* __restrict__ degg) {
    int n = blockIdx.x * 256 + threadIdx.x;
    if (n >= NN) return;
    atomicAdd(&degg[clampi(batch[n], 0, NG - 1)], 1);
}

// ---------------- 3-phase multi-block exclusive scan ----------------
// phase 1: per-block partial sums
__global__ __launch_bounds__(256) void k_scan_part(const int* __restrict__ deg, int* __restrict__ part, int n) {
    __shared__ int red[256];
    int b = blockIdx.x, t = threadIdx.x;
    int chunk = (n + SCB - 1) / SCB;
    int lo = b * chunk, hi = lo + chunk; if (hi > n) hi = n;
    int s = 0;
    for (int i = lo + t; i < hi; i += 256) s += deg[i];
    red[t] = s;
    __syncthreads();
    for (int off = 128; off > 0; off >>= 1) {
        if (t < off) red[t] += red[t + off];
        __syncthreads();
    }
    if (t == 0) part[b] = red[0];
}
// phase 2: exclusive scan of the 256 partials (in place)
__global__ __launch_bounds__(256) void k_scan_offsets(int* __restrict__ part) {
    __shared__ int sh[256];
    int t = threadIdx.x;
    sh[t] = part[t];
    __syncthreads();
    for (int off = 1; off < 256; off <<= 1) {
        int v = (t >= off) ? sh[t - off] : 0;
        __syncthreads();
        sh[t] += v;
        __syncthreads();
    }
    part[t] = (t == 0) ? 0 : sh[t - 1];
}
// phase 3: apply — intra-block scan + write start/cursor (cursor may alias deg)
__global__ __launch_bounds__(256) void k_scan_apply(const int* __restrict__ deg, const int* __restrict__ part,
                                                    int* __restrict__ start, int* cursor, int n) {
    __shared__ int sh[256];
    int b = blockIdx.x, t = threadIdx.x;
    int chunk = (n + SCB - 1) / SCB;
    int lo = b * chunk, hi = lo + chunk; if (hi > n) hi = n;
    int sub = (chunk + 255) / 256;
    int slo = lo + t * sub, shi = slo + sub;
    if (slo > hi) slo = hi;
    if (shi > hi) shi = hi;
    int s = 0;
    for (int i = slo; i < shi; ++i) s += deg[i];
    sh[t] = s;
    __syncthreads();
    for (int off = 1; off < 256; off <<= 1) {
        int v = (t >= off) ? sh[t - off] : 0;
        __syncthreads();
        sh[t] += v;
        __syncthreads();
    }
    int run = part[b] + sh[t] - s;   // exclusive prefix for this thread's sub-range
    for (int i = slo; i < shi; ++i) {
        int d = deg[i];              // read before aliased cursor write
        start[i] = run;
        if (cursor) cursor[i] = run;
        run += d;
    }
    if (b == SCB - 1 && t == 255) start[n] = run;
}

__global__ void k_fill(const int* __restrict__ srcH, const int* __restrict__ dstH,
                       int* __restrict__ cursor, int* __restrict__ elist) {
    int e = blockIdx.x * 256 + threadIdx.x;
    if (e >= NE) return;
    int d = (e < HALF) ? dstH[e] : srcH[e - HALF];
    d = clampi(d, 0, NN - 1);
    int pos = atomicAdd(&cursor[d], 1);
    if (pos >= 0 && pos < NE) elist[pos] = e;
}

// ---------------- segment sum: thread per (node, col-quad), bf16 in/out ----------------
__global__ __launch_bounds__(256) void k_segsum2(const unsigned short* __restrict__ h,
                                                 const int* __restrict__ elist,
                                                 const int* __restrict__ start,
                                                 unsigned short* __restrict__ inc) {
    int t = blockIdx.x * 256 + threadIdx.x;
    if (t >= NN * 75) return;
    int n = t / 75, q = t - n * 75;
    int lo = clampi(start[n], 0, NE), hi = clampi(start[n + 1], 0, NE);
    float4 acc = make_float4(0.f, 0.f, 0.f, 0.f);
    for (int j = lo; j < hi; ++j) {
        int e = clampi(elist[j], 0, NE - 1);
        float4 v = ld4(&h[(size_t)e * 300 + q * 4]);
        acc.x += v.x; acc.y += v.y; acc.z += v.z; acc.w += v.w;
    }
    st4(&inc[(size_t)n * 300 + q * 4], acc);
}

// ================= GEMM core (proven round 10) =================
// 512 threads = 8 waves; M-tile = 64 rows; wave w owns ct = w + 8c (c<3, ct<19).
// Per kt: wave loads its <=3 B hi/lo tile pairs into VGPRs ONCE, reuses over 4 rt.

// ---------------- lin GEMM: h[e] = relu(concat(node_in[src[e]], ea[e]) @ W + b) ----------------
template <int NID, typename TN>
__global__ __launch_bounds__(512, 4) void k_lin_mfma(
        const TN* __restrict__ node_in, const float* __restrict__ ea,
        const int* __restrict__ srcH, const int* __restrict__ dstH,
        const unsigned short* __restrict__ whi, const unsigned short* __restrict__ wlo,
        const float* __restrict__ bias, unsigned short* __restrict__ h) {
    constexpr int K = NID + 14;
    constexpr int KP = (K + 31) & ~31;                    // 160 or 320
    constexpr int NKT = KP / 32;
    constexpr int LDK = (KP + 8 < 312) ? 312 : KP + 8;
    __shared__ unsigned short As[64 * LDK];
    __shared__ int ssrc[64];
    const int tid = threadIdx.x;
    const int lane = tid & 63, wv = tid >> 6;
    const int quad = lane >> 4, cr = lane & 15;
    const int e0 = blockIdx.x * 64;
    if (tid < 64) {
        int e = e0 + tid;
        int s = (e < HALF) ? srcH[e] : dstH[e - HALF];
        ssrc[tid] = clampi(s, 0, NN - 1);
    }
    __syncthreads();
    for (int idx = tid; idx < 64 * KP; idx += 512) {
        int r = idx / KP, k = idx - r * KP;
        float v;
        if (k < NID)    v = ld1(&node_in[(size_t)ssrc[r] * NID + k]);
        else if (k < K) v = ea[(size_t)(e0 + r) * 14 + (k - NID)];
        else            v = 0.f;
        As[r * LDK + k] = f2bf_us(v);
    }
    __syncthreads();
    f32x4v acc[4][3];
    #pragma unroll
    for (int c = 0; c < 3; ++c) {
        int ct = wv + 8 * c;
        float b = 0.f;
        if (ct < 19) { int col = ct * 16 + cr; if (col < 300) b = bias[col]; }
        #pragma unroll
        for (int rt = 0; rt < 4; ++rt) { f32x4v a = {b, b, b, b}; acc[rt][c] = a; }
    }
    for (int kt = 0; kt < NKT; ++kt) {
        bf16x8v bhi[3], blo[3];
        #pragma unroll
        for (int c = 0; c < 3; ++c) {
            int ct = wv + 8 * c;
            if (ct < 19) {
                size_t base = ((size_t)(kt * 19 + ct) * 64 + lane) * 8;
                bhi[c] = *(const bf16x8v*)&whi[base];
                blo[c] = *(const bf16x8v*)&wlo[base];
            }
        }
        #pragma unroll
        for (int rt = 0; rt < 4; ++rt) {
            bf16x8v a = *(const bf16x8v*)&As[(rt * 16 + cr) * LDK + kt * 32 + quad * 8];
            #pragma unroll
            for (int c = 0; c < 3; ++c) {
                int ct = wv + 8 * c;
                if (ct >= 19) break;
                acc[rt][c] = __builtin_amdgcn_mfma_f32_16x16x32_bf16(a, blo[c], acc[rt][c], 0, 0, 0);
                acc[rt][c] = __builtin_amdgcn_mfma_f32_16x16x32_bf16(a, bhi[c], acc[rt][c], 0, 0, 0);
            }
        }
    }
    __syncthreads();
    #pragma unroll
    for (int c = 0; c < 3; ++c) {
        int ct = wv + 8 * c;
        if (ct >= 19) break;
        int col = ct * 16 + cr;
        if (col >= 300) continue;
        #pragma unroll
        for (int rt = 0; rt < 4; ++rt)
            #pragma unroll
            for (int r = 0; r < 4; ++r)
                As[(rt * 16 + quad * 4 + r) * LDK + col] = f2bf_us(fmaxf(acc[rt][c][r], 0.f));
    }
    __syncthreads();
    for (int idx = tid; idx < 64 * 75; idx += 512) {
        int r = idx / 75, q = idx - r * 75;
        *(ushort4*)&h[(size_t)(e0 + r) * 300 + q * 4] = *(const ushort4*)&As[r * LDK + q * 4];
    }
}

// ---------------- au GEMM: out[n] = (relu?)(concat(node_in[n], inc[n]) @ W + b) ----------------
template <int NID, typename TN, bool RELU>
__global__ __launch_bounds__(512, 4) void k_au_mfma(
        const TN* __restrict__ node_in, const unsigned short* __restrict__ inc,
        const unsigned short* __restrict__ whi, const unsigned short* __restrict__ wlo,
        const float* __restrict__ bias, unsigned short* __restrict__ out_rows) {
    constexpr int K = NID + 300;
    constexpr int KP = (K + 31) & ~31;     // 448 or 608
    constexpr int NKT = KP / 32;
    constexpr int LDK = KP + 8;            // 456 / 616
    __shared__ unsigned short As[64 * LDK];
    const int tid = threadIdx.x;
    const int lane = tid & 63, wv = tid >> 6;
    const int quad = lane >> 4, cr = lane & 15;
    const int n0 = blockIdx.x * 64;
    for (int idx = tid; idx < 64 * KP; idx += 512) {
        int r = idx / KP, k = idx - r * KP;
        int n = n0 + r;
        float v;
        if (k < NID)    v = ld1(&node_in[(size_t)n * NID + k]);
        else if (k < K) v = ld1(&inc[(size_t)n * 300 + (k - NID)]);
        else            v = 0.f;
        As[r * LDK + k] = f2bf_us(v);
    }
    __syncthreads();
    f32x4v acc[4][3];
    #pragma unroll
    for (int c = 0; c < 3; ++c) {
        int ct = wv + 8 * c;
        float b = 0.f;
        if (ct < 19) { int col = ct * 16 + cr; if (col < 300) b = bias[col]; }
        #pragma unroll
        for (int rt = 0; rt < 4; ++rt) { f32x4v a = {b, b, b, b}; acc[rt][c] = a; }
    }
    for (int kt = 0; kt < NKT; ++kt) {
        bf16x8v bhi[3], blo[3];
        #pragma unroll
        for (int c = 0; c < 3; ++c) {
            int ct = wv + 8 * c;
            if (ct < 19) {
                size_t base = ((size_t)(kt * 19 + ct) * 64 + lane) * 8;
                bhi[c] = *(const bf16x8v*)&whi[base];
                blo[c] = *(const bf16x8v*)&wlo[base];
            }
        }
        #pragma unroll
        for (int rt = 0; rt < 4; ++rt) {
            bf16x8v a = *(const bf16x8v*)&As[(rt * 16 + cr) * LDK + kt * 32 + quad * 8];
            #pragma unroll
            for (int c = 0; c < 3; ++c) {
                int ct = wv + 8 * c;
                if (ct >= 19) break;
                acc[rt][c] = __builtin_amdgcn_mfma_f32_16x16x32_bf16(a, blo[c], acc[rt][c], 0, 0, 0);
                acc[rt][c] = __builtin_amdgcn_mfma_f32_16x16x32_bf16(a, bhi[c], acc[rt][c], 0, 0, 0);
            }
        }
    }
    __syncthreads();
    #pragma unroll
    for (int c = 0; c < 3; ++c) {
        int ct = wv + 8 * c;
        if (ct >= 19) break;
        int col = ct * 16 + cr;
        if (col >= 300) continue;
        #pragma unroll
        for (int rt = 0; rt < 4; ++rt)
            #pragma unroll
            for (int r = 0; r < 4; ++r) {
                float v = acc[rt][c][r];
                As[(rt * 16 + quad * 4 + r) * LDK + col] = f2bf_us(RELU ? fmaxf(v, 0.f) : v);
            }
    }
    __syncthreads();
    for (int idx = tid; idx < 64 * 75; idx += 512) {
        int r = idx / 75, q = idx - r * 75;
        *(ushort4*)&out_rows[(size_t)(n0 + r) * 300 + q * 4] = *(const ushort4*)&As[r * LDK + q * 4];
    }
}

// ---------------- mp GEMM: h[e] = relu(h[e] + (inc[src[e]] - h[rev(e)]) @ W + b) ----------------
// 64 rows = 32 pairs / block (pair r <-> r+32)
__global__ __launch_bounds__(512, 4) void k_mp_mfma(
        unsigned short* __restrict__ h, const unsigned short* __restrict__ inc,
        const int* __restrict__ srcH, const int* __restrict__ dstH,
        const unsigned short* __restrict__ whi, const unsigned short* __restrict__ wlo,
        const float* __restrict__ bias) {
    constexpr int LDK = 328;
    __shared__ unsigned short Hs[64 * LDK];
    __shared__ int ssrc[64];
    const int tid = threadIdx.x;
    const int lane = tid & 63, wv = tid >> 6;
    const int quad = lane >> 4, cr = lane & 15;
    const int p0 = blockIdx.x * 32;
    if (tid < 64) {
        int r = tid;
        int e = (r < 32) ? (p0 + r) : (p0 + r - 32 + HALF);
        int s = (e < HALF) ? srcH[e] : dstH[e - HALF];
        ssrc[r] = clampi(s, 0, NN - 1);
    }
    for (int idx = tid; idx < 64 * 82; idx += 512) {
        int r = idx / 82, q = idx - r * 82;
        int col = q * 4;
        ushort4 v = make_ushort4(0, 0, 0, 0);
        if (col < 300) {
            int e = (r < 32) ? (p0 + r) : (p0 + r - 32 + HALF);
            v = *(const ushort4*)&h[(size_t)e * 300 + col];
        }
        *(ushort4*)&Hs[r * LDK + col] = v;
    }
    __syncthreads();
    f32x4v acc[4][3];
    #pragma unroll
    for (int c = 0; c < 3; ++c) {
        int ct = wv + 8 * c;
        int col = ct * 16 + cr;
        bool ok = (ct < 19) && (col < 300);
        float b = ok ? bias[col] : 0.f;
        #pragma unroll
        for (int rt = 0; rt < 4; ++rt) {
            f32x4v a = {0.f, 0.f, 0.f, 0.f};
            if (ok) {
                #pragma unroll
                for (int r = 0; r < 4; ++r)
                    a[r] = bf2f_us(Hs[(rt * 16 + quad * 4 + r) * LDK + col]) + b;
            }
            acc[rt][c] = a;
        }
    }
    __syncthreads();
    for (int idx = tid; idx < 32 * 75; idx += 512) {
        int r = idx / 75, q = idx - r * 75;
        int col = q * 4;
        float4 a = ld4(&Hs[r * LDK + col]);
        float4 b = ld4(&Hs[(r + 32) * LDK + col]);
        float4 i1 = ld4(&inc[(size_t)ssrc[r] * 300 + col]);
        float4 i2 = ld4(&inc[(size_t)ssrc[r + 32] * 300 + col]);
        st4(&Hs[r * LDK + col],        make_float4(i1.x - b.x, i1.y - b.y, i1.z - b.z, i1.w - b.w));
        st4(&Hs[(r + 32) * LDK + col], make_float4(i2.x - a.x, i2.y - a.y, i2.z - a.z, i2.w - a.w));
    }
    __syncthreads();
    for (int kt = 0; kt < 10; ++kt) {
        bf16x8v bhi[3], blo[3];
        #pragma unroll
        for (int c = 0; c < 3; ++c) {
            int ct = wv + 8 * c;
            if (ct < 19) {
                size_t base = ((size_t)(kt * 19 + ct) * 64 + lane) * 8;
                bhi[c] = *(const bf16x8v*)&whi[base];
                blo[c] = *(const bf16x8v*)&wlo[base];
            }
        }
        #pragma unroll
        for (int rt = 0; rt < 4; ++rt) {
            bf16x8v a = *(const bf16x8v*)&Hs[(rt * 16 + cr) * LDK + kt * 32 + quad * 8];
            #pragma unroll
            for (int c = 0; c < 3; ++c) {
                int ct = wv + 8 * c;
                if (ct >= 19) break;
                acc[rt][c] = __builtin_amdgcn_mfma_f32_16x16x32_bf16(a, blo[c], acc[rt][c], 0, 0, 0);
                acc[rt][c] = __builtin_amdgcn_mfma_f32_16x16x32_bf16(a, bhi[c], acc[rt][c], 0, 0, 0);
            }
        }
    }
    __syncthreads();
    #pragma unroll
    for (int c = 0; c < 3; ++c) {
        int ct = wv + 8 * c;
        if (ct >= 19) break;
        int col = ct * 16 + cr;
        if (col >= 300) continue;
        #pragma unroll
        for (int rt = 0; rt < 4; ++rt)
            #pragma unroll
            for (int r = 0; r < 4; ++r)
                Hs[(rt * 16 + quad * 4 + r) * LDK + col] = f2bf_us(fmaxf(acc[rt][c][r], 0.f));
    }
    __syncthreads();
    for (int idx = tid; idx < 64 * 75; idx += 512) {
        int r = idx / 75, q = idx - r * 75;
        int e = (r < 32) ? (p0 + r) : (p0 + r - 32 + HALF);
        *(ushort4*)&h[(size_t)e * 300 + q * 4] = *(const ushort4*)&Hs[r * LDK + q * 4];
    }
}

// ---------------- pooling (bf16 rows) + reparam ----------------
__global__ __launch_bounds__(320) void k_pool(const unsigned short* __restrict__ rows,
                                              const float* __restrict__ wat,
                                              const int* __restrict__ gs, float* __restrict__ outg) {
    int g = blockIdx.x, c = threadIdx.x;
    if (c >= 300) return;
    int lo = clampi(gs[g], 0, NN), hi = clampi(gs[g + 1], 0, NN);
    float acc = 0.f;
    for (int n = lo; n < hi; ++n)
        acc += bf2f_us(rows[(size_t)n * 300 + c]) * wat[n];
    float cn = fmaxf((float)(hi - lo), 1.f);
    outg[g * 300 + c] = acc / cn;
}
__global__ __launch_bounds__(320) void k_final(const float* __restrict__ mu_g, const float* __restrict__ lv_g,
                                               const float* __restrict__ eps, float* __restrict__ out) {
    int g = blockIdx.x, c = threadIdx.x;
    if (c >= 300) return;
    out[g * 300 + c] = mu_g[g * 300 + c] + expf(0.5f * lv_g[g * 300 + c]) * eps[g * 300 + c];
}

extern "C" void kernel_launch(void* const* d_in, const int* in_sizes, int n_in,
                              void* d_out, int out_size, void* d_ws, size_t ws_size,
                              hipStream_t stream) {
    float* outp = (float*)d_out;

    const size_t NEED = 199500000ull;   // carve ~199.43 MB; ws proven >= 200,000,000
    if (ws_size < NEED) {
        k_zerof<<<(out_size + 255) / 256, 256, 0, stream>>>(outp, out_size);
        return;
    }

    const float* x   = (const float*)d_in[0];
    const float* ea  = (const float*)d_in[1];
    const float* wat = (const float*)d_in[2];
    const float* eps = (const float*)d_in[3];
    const int* srcH  = (const int*)d_in[4];
    const int* dstH  = (const int*)d_in[5];
    const int* batch = (const int*)d_in[6];
    const float* w_t_lin  = (const float*)d_in[7];
    const float* b_t_lin  = (const float*)d_in[8];
    const float* w_t_mp   = (const float*)d_in[9];
    const float* b_t_mp   = (const float*)d_in[10];
    const float* w_t_au   = (const float*)d_in[11];
    const float* b_t_au   = (const float*)d_in[12];
    const float* w_mu_lin = (const float*)d_in[13];
    const float* b_mu_lin = (const float*)d_in[14];
    const float* w_mu_mp  = (const float*)d_in[15];
    const float* b_mu_mp  = (const float*)d_in[16];
    const float* w_mu_au  = (const float*)d_in[17];
    const float* b_mu_au  = (const float*)d_in[18];
    const float* w_lv_lin = (const float*)d_in[19];
    const float* b_lv_lin = (const float*)d_in[20];
    const float* w_lv_mp  = (const float*)d_in[21];
    const float* b_lv_mp  = (const float*)d_in[22];
    const float* w_lv_au  = (const float*)d_in[23];
    const float* b_lv_au  = (const float*)d_in[24];

    char* p = (char*)d_ws;
    auto alloc = [&](size_t nbytes) { char* q = p; p += (nbytes + 255) & ~(size_t)255; return q; };
    unsigned short* h   = (unsigned short*)alloc((size_t)NE * 300 * 2);   // 96 MB; tail reused as bf16 rows
    unsigned short* inc = (unsigned short*)alloc((size_t)NN * 300 * 2);   // 48 MB
    unsigned short* sh  = (unsigned short*)alloc((size_t)NN * 300 * 2);   // 48 MB
    const size_t MPU = (size_t)3 * 10 * 19 * 512;   // mp tables (ushorts)
    unsigned short* wh_mp = (unsigned short*)alloc(MPU * 2);
    unsigned short* wl_mp = (unsigned short*)alloc(MPU * 2);
    const size_t LAU = (size_t)29 * 19 * 512;       // lin+au tables
    unsigned short* wh_la = (unsigned short*)alloc(LAU * 2);
    unsigned short* wl_la = (unsigned short*)alloc(LAU * 2);
    float* mu_g = (float*)alloc((size_t)NG * 300 * 4);
    float* lv_g = (float*)alloc((size_t)NG * 300 * 4);
    int* deg    = (int*)alloc(NN * 4);               // reused as cursor (alias-safe)
    int* startA = (int*)alloc((NN + 1) * 4);
    int* elist  = (int*)alloc(NE * 4);
    int* degg   = (int*)alloc(NG * 4);
    int* gs     = (int*)alloc((NG + 1) * 4);
    int* part   = (int*)alloc(SCB * 4);

    // ---- CSR (incoming by dst), multi-block scan; cursor aliases deg ----
    k_zeroi<<<(NN + 255) / 256, 256, 0, stream>>>(deg, NN);
    k_hist<<<(NE + 255) / 256, 256, 0, stream>>>(srcH, dstH, deg);
    k_scan_part<<<SCB, 256, 0, stream>>>(deg, part, NN);
    k_scan_offsets<<<1, 256, 0, stream>>>(part);
    k_scan_apply<<<SCB, 256, 0, stream>>>(deg, part, startA, deg, NN);
    k_fill<<<(NE + 255) / 256, 256, 0, stream>>>(srcH, dstH, deg, elist);
    // ---- graph-CSR over sorted batch ----
    k_zeroi<<<(NG + 255) / 256, 256, 0, stream>>>(degg, NG);
    k_histg<<<(NN + 255) / 256, 256, 0, stream>>>(batch, degg);
    k_scan_part<<<SCB, 256, 0, stream>>>(degg, part, NG);
    k_scan_offsets<<<1, 256, 0, stream>>>(part);
    k_scan_apply<<<SCB, 256, 0, stream>>>(degg, part, gs, (int*)nullptr, NG);

    const int SSG = (NN * 75 + 255) / 256;
    const size_t MP_L = (size_t)10 * 19 * 512;      // ushorts per mp layer
    unsigned short* rows = h;                        // bf16 rows alias (h dead at that point)
    auto wsplit = [&](const float* W, int K, int nkt, unsigned short* whi, unsigned short* wlo) {
        k_wsplit_g<<<(nkt * 19 * 64 + 255) / 256, 256, 0, stream>>>(W, K, nkt, whi, wlo);
    };

    // ================= conv t =================
    for (int i = 0; i < 3; ++i)
        wsplit(w_t_mp + i * 90000, 300, 10, wh_mp + i * MP_L, wl_mp + i * MP_L);
    wsplit(w_t_lin, 147, 5, wh_la, wl_la);
    const size_t AU_T = (size_t)5 * 19 * 512;
    wsplit(w_t_au, 433, 14, wh_la + AU_T, wl_la + AU_T);
    k_lin_mfma<133, float><<<NE / 64, 512, 0, stream>>>(x, ea, srcH, dstH, wh_la, wl_la, b_t_lin, h);
    for (int i = 0; i < 3; ++i) {
        k_segsum2<<<SSG, 256, 0, stream>>>(h, elist, startA, inc);
        k_mp_mfma<<<HALF / 32, 512, 0, stream>>>(h, inc, srcH, dstH,
                                                 wh_mp + i * MP_L, wl_mp + i * MP_L, b_t_mp + i * 300);
    }
    k_segsum2<<<SSG, 256, 0, stream>>>(h, elist, startA, inc);
    k_au_mfma<133, float, true><<<NN / 64, 512, 0, stream>>>(x, inc, wh_la + AU_T, wl_la + AU_T, b_t_au, sh);

    // ================= conv mu =================
    for (int i = 0; i < 3; ++i)
        wsplit(w_mu_mp + i * 90000, 300, 10, wh_mp + i * MP_L, wl_mp + i * MP_L);
    wsplit(w_mu_lin, 314, 10, wh_la, wl_la);
    const size_t AU_MU = (size_t)10 * 19 * 512;
    wsplit(w_mu_au, 600, 19, wh_la + AU_MU, wl_la + AU_MU);
    k_lin_mfma<300, unsigned short><<<NE / 64, 512, 0, stream>>>(sh, ea, srcH, dstH, wh_la, wl_la, b_mu_lin, h);
    for (int i = 0; i < 3; ++i) {
        k_segsum2<<<SSG, 256, 0, stream>>>(h, elist, startA, inc);
        k_mp_mfma<<<HALF / 32, 512, 0, stream>>>(h, inc, srcH, dstH,
                                                 wh_mp + i * MP_L, wl_mp + i * MP_L, b_mu_mp + i * 300);
    }
    k_segsum2<<<SSG, 256, 0, stream>>>(h, elist, startA, inc);
    k_au_mfma<300, unsigned short, false><<<NN / 64, 512, 0, stream>>>(sh, inc, wh_la + AU_MU, wl_la + AU_MU, b_mu_au, rows);
    k_pool<<<NG, 320, 0, stream>>>(rows, wat, gs, mu_g);

    // ================= conv lv =================
    for (int i = 0; i < 3; ++i)
        wsplit(w_lv_mp + i * 90000, 300, 10, wh_mp + i * MP_L, wl_mp + i * MP_L);
    wsplit(w_lv_lin, 314, 10, wh_la, wl_la);
    wsplit(w_lv_au, 600, 19, wh_la + AU_MU, wl_la + AU_MU);
    k_lin_mfma<300, unsigned short><<<NE / 64, 512, 0, stream>>>(sh, ea, srcH, dstH, wh_la, wl_la, b_lv_lin, h);
    for (int i = 0; i < 3; ++i) {
        k_segsum2<<<SSG, 256, 0, stream>>>(h, elist, startA, inc);
        k_mp_mfma<<<HALF / 32, 512, 0, stream>>>(h, inc, srcH, dstH,
                                                 wh_mp + i * MP_L, wl_mp + i * MP_L, b_lv_mp + i * 300);
    }
    k_segsum2<<<SSG, 256, 0, stream>>>(h, elist, startA, inc);
    k_au_mfma<300, unsigned short, false><<<NN / 64, 512, 0, stream>>>(sh, inc, wh_la + AU_MU, wl_la + AU_MU, b_lv_au, rows);
    k_pool<<<NG, 320, 0, stream>>>(rows, wat, gs, lv_g);

    // ---- reparam ----
    k_final<<<NG, 320, 0, stream>>>(mu_g, lv_g, eps, outp);
}

// Round 12
// 2260.450 us; speedup vs baseline: 1.8916x; 1.0897x over previous
//
#include <hip/hip_runtime.h>
#include <hip/hip_bf16.h>

#define NN 80000       // nodes
#define NE 160000      // edges (both directions)
#define HALF 80000
#define HID 300
#define NG 1600
#define SCB 256        // scan blocks

typedef __attribute__((ext_vector_type(8))) short bf16x8v;
typedef __attribute__((ext_vector_type(4))) float f32x4v;

// ---------------- helpers ----------------
__device__ __forceinline__ float bf2f_us(unsigned short u) {
    return __uint_as_float(((unsigned int)u) << 16);
}
__device__ __forceinline__ unsigned short f2bf_us(float f) {
    unsigned int u = __float_as_uint(f);
    u += 0x7fff + ((u >> 16) & 1);   // RNE
    return (unsigned short)(u >> 16);
}
__device__ __forceinline__ float ld1(const float* p) { return *p; }
__device__ __forceinline__ float ld1(const unsigned short* p) { return bf2f_us(*p); }
__device__ __forceinline__ void st1(float* p, float v) { *p = v; }
__device__ __forceinline__ void st1(unsigned short* p, float v) { *p = f2bf_us(v); }
__device__ __forceinline__ float4 ld4(const float* p) { return *(const float4*)p; }
__device__ __forceinline__ float4 ld4(const unsigned short* p) {
    ushort4 u = *(const ushort4*)p;
    return make_float4(bf2f_us(u.x), bf2f_us(u.y), bf2f_us(u.z), bf2f_us(u.w));
}
__device__ __forceinline__ void st4(float* p, float4 v) { *(float4*)p = v; }
__device__ __forceinline__ void st4(unsigned short* p, float4 v) {
    ushort4 u; u.x = f2bf_us(v.x); u.y = f2bf_us(v.y); u.z = f2bf_us(v.z); u.w = f2bf_us(v.w);
    *(ushort4*)p = u;
}
__device__ __forceinline__ int clampi(int v, int lo, int hi) {
    return v < lo ? lo : (v > hi ? hi : v);
}

// ---------------- zero-fill ----------------
__global__ void k_zerof(float* __restrict__ p, int n) {
    int i = blockIdx.x * 256 + threadIdx.x; if (i < n) p[i] = 0.f;
}
__global__ void k_zeroi(int* __restrict__ p, int n) {
    int i = blockIdx.x * 256 + threadIdx.x; if (i < n) p[i] = 0;
}

// ---------------- W split+swizzle: K x 300 fp32 -> hi/lo bf16 fragment order ----------------
__global__ void k_wsplit_g(const float* __restrict__ W, int Krows, int nkt,
                           unsigned short* __restrict__ whi, unsigned short* __restrict__ wlo) {
    int idx = blockIdx.x * 256 + threadIdx.x;
    if (idx >= nkt * 19 * 64) return;
    int lane = idx & 63;
    int t = idx >> 6;                 // kt*19 + ct
    int kt = t / 19, ct = t - kt * 19;
    int quad = lane >> 4, cr = lane & 15;
    size_t obase = ((size_t)t * 64 + lane) * 8;
    for (int j = 0; j < 8; ++j) {
        int k = kt * 32 + quad * 8 + j;
        int n = ct * 16 + cr;
        float v = (k < Krows && n < 300) ? W[(size_t)k * 300 + n] : 0.f;
        unsigned short hu = f2bf_us(v);
        unsigned short lu = f2bf_us(v - bf2f_us(hu));
        whi[obase + j] = hu;
        wlo[obase + j] = lu;
    }
}

// ---------------- CSR build ----------------
__global__ void k_hist(const int* __restrict__ srcH, const int* __restrict__ dstH, int* __restrict__ deg) {
    int e = blockIdx.x * 256 + threadIdx.x;
    if (e >= NE) return;
    int d = (e < HALF) ? dstH[e] : srcH[e - HALF];
    d = clampi(d, 0, NN - 1);
    atomicAdd(&deg[d], 1);
}
__global__ void k_histg(const int* __restrict__ batch, int* __restrict__ degg) {
    int n = blockIdx.x * 256 + threadIdx.x;
    if (n >= NN) return;
    atomicAdd(&degg[clampi(batch[n], 0, NG - 1)], 1);
}

// ---------------- 3-phase multi-block exclusive scan (proven round 11) ----------------
__global__ __launch_bounds__(256) void k_scan_part(const int* __restrict__ deg, int* __restrict__ part, int n) {
    __shared__ int red[256];
    int b = blockIdx.x, t = threadIdx.x;
    int chunk = (n + SCB - 1) / SCB;
    int lo = b * chunk, hi = lo + chunk; if (hi > n) hi = n;
    int s = 0;
    for (int i = lo + t; i < hi; i += 256) s += deg[i];
    red[t] = s;
    __syncthreads();
    for (int off = 128; off > 0; off >>= 1) {
        if (t < off) red[t] += red[t + off];
        __syncthreads();
    }
    if (t == 0) part[b] = red[0];
}
__global__ __launch_bounds__(256) void k_scan_offsets(int* __restrict__ part) {
    __shared__ int sh[256];
    int t = threadIdx.x;
    sh[t] = part[t];
    __syncthreads();
    for (int off = 1; off < 256; off <<= 1) {
        int v = (t >= off) ? sh[t - off] : 0;
        __syncthreads();
        sh[t] += v;
        __syncthreads();
    }
    part[t] = (t == 0) ? 0 : sh[t - 1];
}
__global__ __launch_bounds__(256) void k_scan_apply(const int* __restrict__ deg, const int* __restrict__ part,
                                                    int* __restrict__ start, int* cursor, int n) {
    __shared__ int sh[256];
    int b = blockIdx.x, t = threadIdx.x;
    int chunk = (n + SCB - 1) / SCB;
    int lo = b * chunk, hi = lo + chunk; if (hi > n) hi = n;
    int sub = (chunk + 255) / 256;
    int slo = lo + t * sub, shi = slo + sub;
    if (slo > hi) slo = hi;
    if (shi > hi) shi = hi;
    int s = 0;
    for (int i = slo; i < shi; ++i) s += deg[i];
    sh[t] = s;
    __syncthreads();
    for (int off = 1; off < 256; off <<= 1) {
        int v = (t >= off) ? sh[t - off] : 0;
        __syncthreads();
        sh[t] += v;
        __syncthreads();
    }
    int run = part[b] + sh[t] - s;
    for (int i = slo; i < shi; ++i) {
        int d = deg[i];              // read before aliased cursor write
        start[i] = run;
        if (cursor) cursor[i] = run;
        run += d;
    }
    if (b == SCB - 1 && t == 255) start[n] = run;
}

__global__ void k_fill(const int* __restrict__ srcH, const int* __restrict__ dstH,
                       int* __restrict__ cursor, int* __restrict__ elist) {
    int e = blockIdx.x * 256 + threadIdx.x;
    if (e >= NE) return;
    int d = (e < HALF) ? dstH[e] : srcH[e - HALF];
    d = clampi(d, 0, NN - 1);
    int pos = atomicAdd(&cursor[d], 1);
    if (pos >= 0 && pos < NE) elist[pos] = e;
}

// ---------------- segment sum (pre-mp only): thread per (node, col-quad) ----------------
__global__ __launch_bounds__(256) void k_segsum2(const unsigned short* __restrict__ h,
                                                 const int* __restrict__ elist,
                                                 const int* __restrict__ start,
                                                 unsigned short* __restrict__ inc) {
    int t = blockIdx.x * 256 + threadIdx.x;
    if (t >= NN * 75) return;
    int n = t / 75, q = t - n * 75;
    int lo = clampi(start[n], 0, NE), hi = clampi(start[n + 1], 0, NE);
    float4 acc = make_float4(0.f, 0.f, 0.f, 0.f);
    for (int j = lo; j < hi; ++j) {
        int e = clampi(elist[j], 0, NE - 1);
        float4 v = ld4(&h[(size_t)e * 300 + q * 4]);
        acc.x += v.x; acc.y += v.y; acc.z += v.z; acc.w += v.w;
    }
    st4(&inc[(size_t)n * 300 + q * 4], acc);
}

// ================= GEMM core (proven round 10/11) =================
// 512 threads = 8 waves; M-tile = 64 rows; wave w owns ct = w + 8c (c<3, ct<19).
// Per kt: wave loads its <=3 B hi/lo tile pairs into VGPRs ONCE, reuses over 4 rt.

// ---------------- lin GEMM: h[e] = relu(concat(node_in[src[e]], ea[e]) @ W + b) ----------------
template <int NID, typename TN>
__global__ __launch_bounds__(512, 4) void k_lin_mfma(
        const TN* __restrict__ node_in, const float* __restrict__ ea,
        const int* __restrict__ srcH, const int* __restrict__ dstH,
        const unsigned short* __restrict__ whi, const unsigned short* __restrict__ wlo,
        const float* __restrict__ bias, unsigned short* __restrict__ h) {
    constexpr int K = NID + 14;
    constexpr int KP = (K + 31) & ~31;                    // 160 or 320
    constexpr int NKT = KP / 32;
    constexpr int LDK = (KP + 8 < 312) ? 312 : KP + 8;
    __shared__ unsigned short As[64 * LDK];
    __shared__ int ssrc[64];
    const int tid = threadIdx.x;
    const int lane = tid & 63, wv = tid >> 6;
    const int quad = lane >> 4, cr = lane & 15;
    const int e0 = blockIdx.x * 64;
    if (tid < 64) {
        int e = e0 + tid;
        int s = (e < HALF) ? srcH[e] : dstH[e - HALF];
        ssrc[tid] = clampi(s, 0, NN - 1);
    }
    __syncthreads();
    if constexpr (NID == 300) {
        // bf16 source: pure ushort4 copies for node part
        for (int idx = tid; idx < 64 * 75; idx += 512) {
            int r = idx / 75, q = idx - r * 75;
            *(ushort4*)&As[r * LDK + q * 4] =
                *(const ushort4*)&((const unsigned short*)node_in)[(size_t)ssrc[r] * 300 + q * 4];
        }
        // ea + pad: cols [300, KP)
        for (int idx = tid; idx < 64 * (KP - 300); idx += 512) {
            int r = idx / (KP - 300), k = idx - r * (KP - 300);
            int kk = 300 + k;
            float v = (kk < K) ? ea[(size_t)(e0 + r) * 14 + (kk - 300)] : 0.f;
            As[r * LDK + kk] = f2bf_us(v);
        }
    } else {
        for (int idx = tid; idx < 64 * KP; idx += 512) {
            int r = idx / KP, k = idx - r * KP;
            float v;
            if (k < NID)    v = ld1(&node_in[(size_t)ssrc[r] * NID + k]);
            else if (k < K) v = ea[(size_t)(e0 + r) * 14 + (k - NID)];
            else            v = 0.f;
            As[r * LDK + k] = f2bf_us(v);
        }
    }
    __syncthreads();
    f32x4v acc[4][3];
    #pragma unroll
    for (int c = 0; c < 3; ++c) {
        int ct = wv + 8 * c;
        float b = 0.f;
        if (ct < 19) { int col = ct * 16 + cr; if (col < 300) b = bias[col]; }
        #pragma unroll
        for (int rt = 0; rt < 4; ++rt) { f32x4v a = {b, b, b, b}; acc[rt][c] = a; }
    }
    for (int kt = 0; kt < NKT; ++kt) {
        bf16x8v bhi[3], blo[3];
        #pragma unroll
        for (int c = 0; c < 3; ++c) {
            int ct = wv + 8 * c;
            if (ct < 19) {
                size_t base = ((size_t)(kt * 19 + ct) * 64 + lane) * 8;
                bhi[c] = *(const bf16x8v*)&whi[base];
                blo[c] = *(const bf16x8v*)&wlo[base];
            }
        }
        #pragma unroll
        for (int rt = 0; rt < 4; ++rt) {
            bf16x8v a = *(const bf16x8v*)&As[(rt * 16 + cr) * LDK + kt * 32 + quad * 8];
            #pragma unroll
            for (int c = 0; c < 3; ++c) {
                int ct = wv + 8 * c;
                if (ct >= 19) break;
                acc[rt][c] = __builtin_amdgcn_mfma_f32_16x16x32_bf16(a, blo[c], acc[rt][c], 0, 0, 0);
                acc[rt][c] = __builtin_amdgcn_mfma_f32_16x16x32_bf16(a, bhi[c], acc[rt][c], 0, 0, 0);
            }
        }
    }
    __syncthreads();
    #pragma unroll
    for (int c = 0; c < 3; ++c) {
        int ct = wv + 8 * c;
        if (ct >= 19) break;
        int col = ct * 16 + cr;
        if (col >= 300) continue;
        #pragma unroll
        for (int rt = 0; rt < 4; ++rt)
            #pragma unroll
            for (int r = 0; r < 4; ++r)
                As[(rt * 16 + quad * 4 + r) * LDK + col] = f2bf_us(fmaxf(acc[rt][c][r], 0.f));
    }
    __syncthreads();
    for (int idx = tid; idx < 64 * 75; idx += 512) {
        int r = idx / 75, q = idx - r * 75;
        *(ushort4*)&h[(size_t)(e0 + r) * 300 + q * 4] = *(const ushort4*)&As[r * LDK + q * 4];
    }
}

// ---------------- au GEMM (segsum FUSED): out[n] = (relu?)(concat(node_in[n], segsum_h[n]) @ W + b) ----
template <int NID, typename TN, bool RELU>
__global__ __launch_bounds__(512, 4) void k_au_mfma(
        const TN* __restrict__ node_in, const unsigned short* __restrict__ h,
        const int* __restrict__ elist, const int* __restrict__ start,
        const unsigned short* __restrict__ whi, const unsigned short* __restrict__ wlo,
        const float* __restrict__ bias, unsigned short* __restrict__ out_rows) {
    constexpr int K = NID + 300;
    constexpr int KP = (K + 31) & ~31;     // 448 or 608
    constexpr int NKT = KP / 32;
    constexpr int LDK = KP + 8;            // 456 / 616
    __shared__ unsigned short As[64 * LDK];
    const int tid = threadIdx.x;
    const int lane = tid & 63, wv = tid >> 6;
    const int quad = lane >> 4, cr = lane & 15;
    const int n0 = blockIdx.x * 64;
    // node part: cols [0, NID)
    if constexpr (NID == 300) {
        for (int idx = tid; idx < 64 * 75; idx += 512) {
            int r = idx / 75, q = idx - r * 75;
            *(ushort4*)&As[r * LDK + q * 4] =
                *(const ushort4*)&((const unsigned short*)node_in)[(size_t)(n0 + r) * 300 + q * 4];
        }
    } else {
        for (int idx = tid; idx < 64 * NID; idx += 512) {
            int r = idx / NID, k = idx - r * NID;
            As[r * LDK + k] = f2bf_us(ld1(&node_in[(size_t)(n0 + r) * NID + k]));
        }
    }
    // fused segment-sum gather: cols [NID, NID+300)
    for (int idx = tid; idx < 64 * 75; idx += 512) {
        int r = idx / 75, q = idx - r * 75;
        int n = n0 + r;
        int lo = clampi(start[n], 0, NE), hi = clampi(start[n + 1], 0, NE);
        float4 acc = make_float4(0.f, 0.f, 0.f, 0.f);
        for (int j = lo; j < hi; ++j) {
            int e = clampi(elist[j], 0, NE - 1);
            float4 v = ld4(&h[(size_t)e * 300 + q * 4]);
            acc.x += v.x; acc.y += v.y; acc.z += v.z; acc.w += v.w;
        }
        unsigned short* dst = &As[r * LDK + NID + q * 4];
        dst[0] = f2bf_us(acc.x); dst[1] = f2bf_us(acc.y);
        dst[2] = f2bf_us(acc.z); dst[3] = f2bf_us(acc.w);
    }
    // pad: cols [NID+300, KP)
    constexpr int PAD = KP - NID - 300;
    for (int idx = tid; idx < 64 * PAD; idx += 512) {
        int r = idx / PAD, k = idx - r * PAD;
        As[r * LDK + NID + 300 + k] = 0;
    }
    __syncthreads();
    f32x4v acc[4][3];
    #pragma unroll
    for (int c = 0; c < 3; ++c) {
        int ct = wv + 8 * c;
        float b = 0.f;
        if (ct < 19) { int col = ct * 16 + cr; if (col < 300) b = bias[col]; }
        #pragma unroll
        for (int rt = 0; rt < 4; ++rt) { f32x4v a = {b, b, b, b}; acc[rt][c] = a; }
    }
    for (int kt = 0; kt < NKT; ++kt) {
        bf16x8v bhi[3], blo[3];
        #pragma unroll
        for (int c = 0; c < 3; ++c) {
            int ct = wv + 8 * c;
            if (ct < 19) {
                size_t base = ((size_t)(kt * 19 + ct) * 64 + lane) * 8;
                bhi[c] = *(const bf16x8v*)&whi[base];
                blo[c] = *(const bf16x8v*)&wlo[base];
            }
        }
        #pragma unroll
        for (int rt = 0; rt < 4; ++rt) {
            bf16x8v a = *(const bf16x8v*)&As[(rt * 16 + cr) * LDK + kt * 32 + quad * 8];
            #pragma unroll
            for (int c = 0; c < 3; ++c) {
                int ct = wv + 8 * c;
                if (ct >= 19) break;
                acc[rt][c] = __builtin_amdgcn_mfma_f32_16x16x32_bf16(a, blo[c], acc[rt][c], 0, 0, 0);
                acc[rt][c] = __builtin_amdgcn_mfma_f32_16x16x32_bf16(a, bhi[c], acc[rt][c], 0, 0, 0);
            }
        }
    }
    __syncthreads();
    #pragma unroll
    for (int c = 0; c < 3; ++c) {
        int ct = wv + 8 * c;
        if (ct >= 19) break;
        int col = ct * 16 + cr;
        if (col >= 300) continue;
        #pragma unroll
        for (int rt = 0; rt < 4; ++rt)
            #pragma unroll
            for (int r = 0; r < 4; ++r) {
                float v = acc[rt][c][r];
                As[(rt * 16 + quad * 4 + r) * LDK + col] = f2bf_us(RELU ? fmaxf(v, 0.f) : v);
            }
    }
    __syncthreads();
    for (int idx = tid; idx < 64 * 75; idx += 512) {
        int r = idx / 75, q = idx - r * 75;
        *(ushort4*)&out_rows[(size_t)(n0 + r) * 300 + q * 4] = *(const ushort4*)&As[r * LDK + q * 4];
    }
}

// ---------------- mp GEMM: h[e] = relu(h[e] + (inc[src[e]] - h[rev(e)]) @ W + b) ----------------
// 64 rows = 32 pairs / block (pair r <-> r+32)
__global__ __launch_bounds__(512, 4) void k_mp_mfma(
        unsigned short* __restrict__ h, const unsigned short* __restrict__ inc,
        const int* __restrict__ srcH, const int* __restrict__ dstH,
        const unsigned short* __restrict__ whi, const unsigned short* __restrict__ wlo,
        const float* __restrict__ bias) {
    constexpr int LDK = 328;
    __shared__ unsigned short Hs[64 * LDK];
    __shared__ int ssrc[64];
    const int tid = threadIdx.x;
    const int lane = tid & 63, wv = tid >> 6;
    const int quad = lane >> 4, cr = lane & 15;
    const int p0 = blockIdx.x * 32;
    if (tid < 64) {
        int r = tid;
        int e = (r < 32) ? (p0 + r) : (p0 + r - 32 + HALF);
        int s = (e < HALF) ? srcH[e] : dstH[e - HALF];
        ssrc[r] = clampi(s, 0, NN - 1);
    }
    for (int idx = tid; idx < 64 * 82; idx += 512) {
        int r = idx / 82, q = idx - r * 82;
        int col = q * 4;
        ushort4 v = make_ushort4(0, 0, 0, 0);
        if (col < 300) {
            int e = (r < 32) ? (p0 + r) : (p0 + r - 32 + HALF);
            v = *(const ushort4*)&h[(size_t)e * 300 + col];
        }
        *(ushort4*)&Hs[r * LDK + col] = v;
    }
    __syncthreads();
    f32x4v acc[4][3];
    #pragma unroll
    for (int c = 0; c < 3; ++c) {
        int ct = wv + 8 * c;
        int col = ct * 16 + cr;
        bool ok = (ct < 19) && (col < 300);
        float b = ok ? bias[col] : 0.f;
        #pragma unroll
        for (int rt = 0; rt < 4; ++rt) {
            f32x4v a = {0.f, 0.f, 0.f, 0.f};
            if (ok) {
                #pragma unroll
                for (int r = 0; r < 4; ++r)
                    a[r] = bf2f_us(Hs[(rt * 16 + quad * 4 + r) * LDK + col]) + b;
            }
            acc[rt][c] = a;
        }
    }
    __syncthreads();
    for (int idx = tid; idx < 32 * 75; idx += 512) {
        int r = idx / 75, q = idx - r * 75;
        int col = q * 4;
        float4 a = ld4(&Hs[r * LDK + col]);
        float4 b = ld4(&Hs[(r + 32) * LDK + col]);
        float4 i1 = ld4(&inc[(size_t)ssrc[r] * 300 + col]);
        float4 i2 = ld4(&inc[(size_t)ssrc[r + 32] * 300 + col]);
        st4(&Hs[r * LDK + col],        make_float4(i1.x - b.x, i1.y - b.y, i1.z - b.z, i1.w - b.w));
        st4(&Hs[(r + 32) * LDK + col], make_float4(i2.x - a.x, i2.y - a.y, i2.z - a.z, i2.w - a.w));
    }
    __syncthreads();
    for (int kt = 0; kt < 10; ++kt) {
        bf16x8v bhi[3], blo[3];
        #pragma unroll
        for (int c = 0; c < 3; ++c) {
            int ct = wv + 8 * c;
            if (ct < 19) {
                size_t base = ((size_t)(kt * 19 + ct) * 64 + lane) * 8;
                bhi[c] = *(const bf16x8v*)&whi[base];
                blo[c] = *(const bf16x8v*)&wlo[base];
            }
        }
        #pragma unroll
        for (int rt = 0; rt < 4; ++rt) {
            bf16x8v a = *(const bf16x8v*)&Hs[(rt * 16 + cr) * LDK + kt * 32 + quad * 8];
            #pragma unroll
            for (int c = 0; c < 3; ++c) {
                int ct = wv + 8 * c;
                if (ct >= 19) break;
                acc[rt][c] = __builtin_amdgcn_mfma_f32_16x16x32_bf16(a, blo[c], acc[rt][c], 0, 0, 0);
                acc[rt][c] = __builtin_amdgcn_mfma_f32_16x16x32_bf16(a, bhi[c], acc[rt][c], 0, 0, 0);
            }
        }
    }
    __syncthreads();
    #pragma unroll
    for (int c = 0; c < 3; ++c) {
        int ct = wv + 8 * c;
        if (ct >= 19) break;
        int col = ct * 16 + cr;
        if (col >= 300) continue;
        #pragma unroll
        for (int rt = 0; rt < 4; ++rt)
            #pragma unroll
            for (int r = 0; r < 4; ++r)
                Hs[(rt * 16 + quad * 4 + r) * LDK + col] = f2bf_us(fmaxf(acc[rt][c][r], 0.f));
    }
    __syncthreads();
    for (int idx = tid; idx < 64 * 75; idx += 512) {
        int r = idx / 75, q = idx - r * 75;
        int e = (r < 32) ? (p0 + r) : (p0 + r - 32 + HALF);
        *(ushort4*)&h[(size_t)e * 300 + q * 4] = *(const ushort4*)&Hs[r * LDK + q * 4];
    }
}

// ---------------- pooling (bf16 rows) + reparam ----------------
__global__ __launch_bounds__(320) void k_pool(const unsigned short* __restrict__ rows,
                                              const float* __restrict__ wat,
                                              const int* __restrict__ gs, float* __restrict__ outg) {
    int g = blockIdx.x, c = threadIdx.x;
    if (c >= 300) return;
    int lo = clampi(gs[g], 0, NN), hi = clampi(gs[g + 1], 0, NN);
    float acc = 0.f;
    for (int n = lo; n < hi; ++n)
        acc += bf2f_us(rows[(size_t)n * 300 + c]) * wat[n];
    float cn = fmaxf((float)(hi - lo), 1.f);
    outg[g * 300 + c] = acc / cn;
}
__global__ __launch_bounds__(320) void k_final(const float* __restrict__ mu_g, const float* __restrict__ lv_g,
                                               const float* __restrict__ eps, float* __restrict__ out) {
    int g = blockIdx.x, c = threadIdx.x;
    if (c >= 300) return;
    out[g * 300 + c] = mu_g[g * 300 + c] + expf(0.5f * lv_g[g * 300 + c]) * eps[g * 300 + c];
}

extern "C" void kernel_launch(void* const* d_in, const int* in_sizes, int n_in,
                              void* d_out, int out_size, void* d_ws, size_t ws_size,
                              hipStream_t stream) {
    float* outp = (float*)d_out;

    const size_t NEED = 199500000ull;   // carve ~199.43 MB; ws proven >= 200,000,000
    if (ws_size < NEED) {
        k_zerof<<<(out_size + 255) / 256, 256, 0, stream>>>(outp, out_size);
        return;
    }

    const float* x   = (const float*)d_in[0];
    const float* ea  = (const float*)d_in[1];
    const float* wat = (const float*)d_in[2];
    const float* eps = (const float*)d_in[3];
    const int* srcH  = (const int*)d_in[4];
    const int* dstH  = (const int*)d_in[5];
    const int* batch = (const int*)d_in[6];
    const float* w_t_lin  = (const float*)d_in[7];
    const float* b_t_lin  = (const float*)d_in[8];
    const float* w_t_mp   = (const float*)d_in[9];
    const float* b_t_mp   = (const float*)d_in[10];
    const float* w_t_au   = (const float*)d_in[11];
    const float* b_t_au   = (const float*)d_in[12];
    const float* w_mu_lin = (const float*)d_in[13];
    const float* b_mu_lin = (const float*)d_in[14];
    const float* w_mu_mp  = (const float*)d_in[15];
    const float* b_mu_mp  = (const float*)d_in[16];
    const float* w_mu_au  = (const float*)d_in[17];
    const float* b_mu_au  = (const float*)d_in[18];
    const float* w_lv_lin = (const float*)d_in[19];
    const float* b_lv_lin = (const float*)d_in[20];
    const float* w_lv_mp  = (const float*)d_in[21];
    const float* b_lv_mp  = (const float*)d_in[22];
    const float* w_lv_au  = (const float*)d_in[23];
    const float* b_lv_au  = (const float*)d_in[24];

    char* p = (char*)d_ws;
    auto alloc = [&](size_t nbytes) { char* q = p; p += (nbytes + 255) & ~(size_t)255; return q; };
    unsigned short* h   = (unsigned short*)alloc((size_t)NE * 300 * 2);   // 96 MB
    unsigned short* inc = (unsigned short*)alloc((size_t)NN * 300 * 2);   // 48 MB; dead during au -> reused as rows
    unsigned short* sh  = (unsigned short*)alloc((size_t)NN * 300 * 2);   // 48 MB
    const size_t MPU = (size_t)3 * 10 * 19 * 512;   // mp tables (ushorts)
    unsigned short* wh_mp = (unsigned short*)alloc(MPU * 2);
    unsigned short* wl_mp = (unsigned short*)alloc(MPU * 2);
    const size_t LAU = (size_t)29 * 19 * 512;       // lin+au tables
    unsigned short* wh_la = (unsigned short*)alloc(LAU * 2);
    unsigned short* wl_la = (unsigned short*)alloc(LAU * 2);
    float* mu_g = (float*)alloc((size_t)NG * 300 * 4);
    float* lv_g = (float*)alloc((size_t)NG * 300 * 4);
    int* deg    = (int*)alloc(NN * 4);               // reused as cursor (alias-safe)
    int* startA = (int*)alloc((NN + 1) * 4);
    int* elist  = (int*)alloc(NE * 4);
    int* degg   = (int*)alloc(NG * 4);
    int* gs     = (int*)alloc((NG + 1) * 4);
    int* part   = (int*)alloc(SCB * 4);

    // ---- CSR (incoming by dst), multi-block scan; cursor aliases deg ----
    k_zeroi<<<(NN + 255) / 256, 256, 0, stream>>>(deg, NN);
    k_hist<<<(NE + 255) / 256, 256, 0, stream>>>(srcH, dstH, deg);
    k_scan_part<<<SCB, 256, 0, stream>>>(deg, part, NN);
    k_scan_offsets<<<1, 256, 0, stream>>>(part);
    k_scan_apply<<<SCB, 256, 0, stream>>>(deg, part, startA, deg, NN);
    k_fill<<<(NE + 255) / 256, 256, 0, stream>>>(srcH, dstH, deg, elist);
    // ---- graph-CSR over sorted batch ----
    k_zeroi<<<(NG + 255) / 256, 256, 0, stream>>>(degg, NG);
    k_histg<<<(NN + 255) / 256, 256, 0, stream>>>(batch, degg);
    k_scan_part<<<SCB, 256, 0, stream>>>(degg, part, NG);
    k_scan_offsets<<<1, 256, 0, stream>>>(part);
    k_scan_apply<<<SCB, 256, 0, stream>>>(degg, part, gs, (int*)nullptr, NG);

    const int SSG = (NN * 75 + 255) / 256;
    const size_t MP_L = (size_t)10 * 19 * 512;      // ushorts per mp layer
    unsigned short* rows = inc;                      // au output aliases inc (dead during au)
    auto wsplit = [&](const float* W, int K, int nkt, unsigned short* whi, unsigned short* wlo) {
        k_wsplit_g<<<(nkt * 19 * 64 + 255) / 256, 256, 0, stream>>>(W, K, nkt, whi, wlo);
    };

    // ================= conv t =================
    for (int i = 0; i < 3; ++i)
        wsplit(w_t_mp + i * 90000, 300, 10, wh_mp + i * MP_L, wl_mp + i * MP_L);
    wsplit(w_t_lin, 147, 5, wh_la, wl_la);
    const size_t AU_T = (size_t)5 * 19 * 512;
    wsplit(w_t_au, 433, 14, wh_la + AU_T, wl_la + AU_T);
    k_lin_mfma<133, float><<<NE / 64, 512, 0, stream>>>(x, ea, srcH, dstH, wh_la, wl_la, b_t_lin, h);
    for (int i = 0; i < 3; ++i) {
        k_segsum2<<<SSG, 256, 0, stream>>>(h, elist, startA, inc);
        k_mp_mfma<<<HALF / 32, 512, 0, stream>>>(h, inc, srcH, dstH,
                                                 wh_mp + i * MP_L, wl_mp + i * MP_L, b_t_mp + i * 300);
    }
    k_au_mfma<133, float, true><<<NN / 64, 512, 0, stream>>>(x, h, elist, startA,
                                                             wh_la + AU_T, wl_la + AU_T, b_t_au, sh);

    // ================= conv mu =================
    for (int i = 0; i < 3; ++i)
        wsplit(w_mu_mp + i * 90000, 300, 10, wh_mp + i * MP_L, wl_mp + i * MP_L);
    wsplit(w_mu_lin, 314, 10, wh_la, wl_la);
    const size_t AU_MU = (size_t)10 * 19 * 512;
    wsplit(w_mu_au, 600, 19, wh_la + AU_MU, wl_la + AU_MU);
    k_lin_mfma<300, unsigned short><<<NE / 64, 512, 0, stream>>>(sh, ea, srcH, dstH, wh_la, wl_la, b_mu_lin, h);
    for (int i = 0; i < 3; ++i) {
        k_segsum2<<<SSG, 256, 0, stream>>>(h, elist, startA, inc);
        k_mp_mfma<<<HALF / 32, 512, 0, stream>>>(h, inc, srcH, dstH,
                                                 wh_mp + i * MP_L, wl_mp + i * MP_L, b_mu_mp + i * 300);
    }
    k_au_mfma<300, unsigned short, false><<<NN / 64, 512, 0, stream>>>(sh, h, elist, startA,
                                                                       wh_la + AU_MU, wl_la + AU_MU, b_mu_au, rows);
    k_pool<<<NG, 320, 0, stream>>>(rows, wat, gs, mu_g);

    // ================= conv lv =================
    for (int i = 0; i < 3; ++i)
        wsplit(w_lv_mp + i * 90000, 300, 10, wh_mp + i * MP_L, wl_mp + i * MP_L);
    wsplit(w_lv_lin, 314, 10, wh_la, wl_la);
    wsplit(w_lv_au, 600, 19, wh_la + AU_MU, wl_la + AU_MU);
    k_lin_mfma<300, unsigned short><<<NE / 64, 512, 0, stream>>>(sh, ea, srcH, dstH, wh_la, wl_la, b_lv_lin, h);
    for (int i = 0; i < 3; ++i) {
        k_segsum2<<<SSG, 256, 0, stream>>>(h, elist, startA, inc);
        k_mp_mfma<<<HALF / 32, 512, 0, stream>>>(h, inc, srcH, dstH,
                                                 wh_mp + i * MP_L, wl_mp + i * MP_L, b_lv_mp + i * 300);
    }
    k_au_mfma<300, unsigned short, false><<<NN / 64, 512, 0, stream>>>(sh, h, elist, startA,
                                                                       wh_la + AU_MU, wl_la + AU_MU, b_lv_au, rows);
    k_pool<<<NG, 320, 0, stream>>>(rows, wat, gs, lv_g);

    // ---- reparam ----
    k_final<<<NG, 320, 0, stream>>>(mu_g, lv_g, eps, outp);
}

// Round 13
// 2050.189 us; speedup vs baseline: 2.0856x; 1.1026x over previous
//
#include <hip/hip_runtime.h>
#include <hip/hip_bf16.h>

#define NN 80000       // nodes
#define NE 160000      // edges (both directions)
#define HALF 80000
#define HID 300
#define NG 1600
#define SCB 256        // scan blocks

typedef __attribute__((ext_vector_type(8))) short bf16x8v;
typedef __attribute__((ext_vector_type(4))) float f32x4v;

// ---------------- helpers ----------------
__device__ __forceinline__ float bf2f_us(unsigned short u) {
    return __uint_as_float(((unsigned int)u) << 16);
}
__device__ __forceinline__ unsigned short f2bf_us(float f) {
    unsigned int u = __float_as_uint(f);
    u += 0x7fff + ((u >> 16) & 1);   // RNE
    return (unsigned short)(u >> 16);
}
__device__ __forceinline__ float ld1(const float* p) { return *p; }
__device__ __forceinline__ float ld1(const unsigned short* p) { return bf2f_us(*p); }
__device__ __forceinline__ void st1(float* p, float v) { *p = v; }
__device__ __forceinline__ void st1(unsigned short* p, float v) { *p = f2bf_us(v); }
__device__ __forceinline__ float4 ld4(const float* p) { return *(const float4*)p; }
__device__ __forceinline__ float4 ld4(const unsigned short* p) {
    ushort4 u = *(const ushort4*)p;
    return make_float4(bf2f_us(u.x), bf2f_us(u.y), bf2f_us(u.z), bf2f_us(u.w));
}
__device__ __forceinline__ void st4(float* p, float4 v) { *(float4*)p = v; }
__device__ __forceinline__ void st4(unsigned short* p, float4 v) {
    ushort4 u; u.x = f2bf_us(v.x); u.y = f2bf_us(v.y); u.z = f2bf_us(v.z); u.w = f2bf_us(v.w);
    *(ushort4*)p = u;
}
__device__ __forceinline__ int clampi(int v, int lo, int hi) {
    return v < lo ? lo : (v > hi ? hi : v);
}

// ---------------- zero-fill ----------------
__global__ void k_zerof(float* __restrict__ p, int n) {
    int i = blockIdx.x * 256 + threadIdx.x; if (i < n) p[i] = 0.f;
}
__global__ void k_zeroi(int* __restrict__ p, int n) {
    int i = blockIdx.x * 256 + threadIdx.x; if (i < n) p[i] = 0;
}

// ---------------- merged per-conv W split: mp(3 layers) + lin + au in ONE dispatch ----------------
// fragment order per tile t: lane holds B[k=kt*32+quad*8+j][n=ct*16+(lane&15)], j=0..7
__global__ void k_wsplit_conv(const float* __restrict__ Wmp,
                              const float* __restrict__ Wlin, int Klin, int nktlin,
                              const float* __restrict__ Wau, int Kau, int nktau,
                              unsigned short* __restrict__ wh_mp, unsigned short* __restrict__ wl_mp,
                              unsigned short* __restrict__ wh_la, unsigned short* __restrict__ wl_la) {
    const int MP_L = 10 * 19 * 512;   // ushorts per mp layer
    int idx = blockIdx.x * 256 + threadIdx.x;
    int total = 570 + nktlin * 19 + nktau * 19;
    int t = idx >> 6;
    if (t >= total) return;
    int lane = idx & 63;
    const float* W; int Krows, ltile;
    unsigned short *whi, *wlo;
    if (t < 570) {                       // mp: 3 layers x 190 tiles
        int l = t / 190, rem = t - l * 190;
        W = Wmp + l * 90000; Krows = 300; ltile = rem;
        whi = wh_mp + l * MP_L; wlo = wl_mp + l * MP_L;
    } else if (t < 570 + nktlin * 19) {  // lin at la offset 0
        ltile = t - 570; W = Wlin; Krows = Klin;
        whi = wh_la; wlo = wl_la;
    } else {                             // au after lin tiles
        ltile = t - 570 - nktlin * 19; W = Wau; Krows = Kau;
        size_t off = (size_t)nktlin * 19 * 512;
        whi = wh_la + off; wlo = wl_la + off;
    }
    int kt = ltile / 19, ct = ltile - kt * 19;
    int quad = lane >> 4, cr = lane & 15;
    size_t obase = ((size_t)ltile * 64 + lane) * 8;
    for (int j = 0; j < 8; ++j) {
        int k = kt * 32 + quad * 8 + j;
        int n = ct * 16 + cr;
        float v = (k < Krows && n < 300) ? W[(size_t)k * 300 + n] : 0.f;
        unsigned short hu = f2bf_us(v);
        unsigned short lu = f2bf_us(v - bf2f_us(hu));
        whi[obase + j] = hu;
        wlo[obase + j] = lu;
    }
}

// ---------------- CSR build ----------------
__global__ void k_hist(const int* __restrict__ srcH, const int* __restrict__ dstH, int* __restrict__ deg) {
    int e = blockIdx.x * 256 + threadIdx.x;
    if (e >= NE) return;
    int d = (e < HALF) ? dstH[e] : srcH[e - HALF];
    d = clampi(d, 0, NN - 1);
    atomicAdd(&deg[d], 1);
}
__global__ void k_histg(const int* __restrict__ batch, int* __restrict__ degg) {
    int n = blockIdx.x * 256 + threadIdx.x;
    if (n >= NN) return;
    atomicAdd(&degg[clampi(batch[n], 0, NG - 1)], 1);
}

// ---------------- 3-phase multi-block exclusive scan (proven round 11) ----------------
__global__ __launch_bounds__(256) void k_scan_part(const int* __restrict__ deg, int* __restrict__ part, int n) {
    __shared__ int red[256];
    int b = blockIdx.x, t = threadIdx.x;
    int chunk = (n + SCB - 1) / SCB;
    int lo = b * chunk, hi = lo + chunk; if (hi > n) hi = n;
    int s = 0;
    for (int i = lo + t; i < hi; i += 256) s += deg[i];
    red[t] = s;
    __syncthreads();
    for (int off = 128; off > 0; off >>= 1) {
        if (t < off) red[t] += red[t + off];
        __syncthreads();
    }
    if (t == 0) part[b] = red[0];
}
__global__ __launch_bounds__(256) void k_scan_offsets(int* __restrict__ part) {
    __shared__ int sh[256];
    int t = threadIdx.x;
    sh[t] = part[t];
    __syncthreads();
    for (int off = 1; off < 256; off <<= 1) {
        int v = (t >= off) ? sh[t - off] : 0;
        __syncthreads();
        sh[t] += v;
        __syncthreads();
    }
    part[t] = (t == 0) ? 0 : sh[t - 1];
}
__global__ __launch_bounds__(256) void k_scan_apply(const int* __restrict__ deg, const int* __restrict__ part,
                                                    int* __restrict__ start, int* cursor, int n) {
    __shared__ int sh[256];
    int b = blockIdx.x, t = threadIdx.x;
    int chunk = (n + SCB - 1) / SCB;
    int lo = b * chunk, hi = lo + chunk; if (hi > n) hi = n;
    int sub = (chunk + 255) / 256;
    int slo = lo + t * sub, shi = slo + sub;
    if (slo > hi) slo = hi;
    if (shi > hi) shi = hi;
    int s = 0;
    for (int i = slo; i < shi; ++i) s += deg[i];
    sh[t] = s;
    __syncthreads();
    for (int off = 1; off < 256; off <<= 1) {
        int v = (t >= off) ? sh[t - off] : 0;
        __syncthreads();
        sh[t] += v;
        __syncthreads();
    }
    int run = part[b] + sh[t] - s;
    for (int i = slo; i < shi; ++i) {
        int d = deg[i];              // read before aliased cursor write
        start[i] = run;
        if (cursor) cursor[i] = run;
        run += d;
    }
    if (b == SCB - 1 && t == 255) start[n] = run;
}

__global__ void k_fill(const int* __restrict__ srcH, const int* __restrict__ dstH,
                       int* __restrict__ cursor, int* __restrict__ elist) {
    int e = blockIdx.x * 256 + threadIdx.x;
    if (e >= NE) return;
    int d = (e < HALF) ? dstH[e] : srcH[e - HALF];
    d = clampi(d, 0, NN - 1);
    int pos = atomicAdd(&cursor[d], 1);
    if (pos >= 0 && pos < NE) elist[pos] = e;
}

// ---------------- segment sum (pre-mp only): thread per (node, col-quad), 2-way unrolled ----------------
__global__ __launch_bounds__(256) void k_segsum2(const unsigned short* __restrict__ h,
                                                 const int* __restrict__ elist,
                                                 const int* __restrict__ start,
                                                 unsigned short* __restrict__ inc) {
    int t = blockIdx.x * 256 + threadIdx.x;
    if (t >= NN * 75) return;
    int n = t / 75, q = t - n * 75;
    int lo = clampi(start[n], 0, NE), hi = clampi(start[n + 1], 0, NE);
    float4 acc = make_float4(0.f, 0.f, 0.f, 0.f);
    int j = lo;
    for (; j + 2 <= hi; j += 2) {
        int e0 = clampi(elist[j], 0, NE - 1);
        int e1 = clampi(elist[j + 1], 0, NE - 1);
        float4 v0 = ld4(&h[(size_t)e0 * 300 + q * 4]);
        float4 v1 = ld4(&h[(size_t)e1 * 300 + q * 4]);
        acc.x += v0.x; acc.y += v0.y; acc.z += v0.z; acc.w += v0.w;
        acc.x += v1.x; acc.y += v1.y; acc.z += v1.z; acc.w += v1.w;
    }
    if (j < hi) {
        int e0 = clampi(elist[j], 0, NE - 1);
        float4 v0 = ld4(&h[(size_t)e0 * 300 + q * 4]);
        acc.x += v0.x; acc.y += v0.y; acc.z += v0.z; acc.w += v0.w;
    }
    st4(&inc[(size_t)n * 300 + q * 4], acc);
}

// ================= GEMM core (proven round 10/11) =================
// 512 threads = 8 waves; M-tile = 64 rows; wave w owns ct = w + 8c (c<3, ct<19).
// Per kt: wave loads its <=3 B hi/lo tile pairs into VGPRs ONCE, reuses over 4 rt.

// ---------------- lin GEMM: h[e] = relu(concat(node_in[src[e]], ea[e]) @ W + b) ----------------
template <int NID, typename TN>
__global__ __launch_bounds__(512, 4) void k_lin_mfma(
        const TN* __restrict__ node_in, const float* __restrict__ ea,
        const int* __restrict__ srcH, const int* __restrict__ dstH,
        const unsigned short* __restrict__ whi, const unsigned short* __restrict__ wlo,
        const float* __restrict__ bias, unsigned short* __restrict__ h) {
    constexpr int K = NID + 14;
    constexpr int KP = (K + 31) & ~31;                    // 160 or 320
    constexpr int NKT = KP / 32;
    constexpr int LDK = (KP + 8 < 312) ? 312 : KP + 8;
    __shared__ unsigned short As[64 * LDK];
    __shared__ int ssrc[64];
    const int tid = threadIdx.x;
    const int lane = tid & 63, wv = tid >> 6;
    const int quad = lane >> 4, cr = lane & 15;
    const int e0 = blockIdx.x * 64;
    if (tid < 64) {
        int e = e0 + tid;
        int s = (e < HALF) ? srcH[e] : dstH[e - HALF];
        ssrc[tid] = clampi(s, 0, NN - 1);
    }
    __syncthreads();
    if constexpr (NID == 300) {
        for (int idx = tid; idx < 64 * 75; idx += 512) {
            int r = idx / 75, q = idx - r * 75;
            *(ushort4*)&As[r * LDK + q * 4] =
                *(const ushort4*)&((const unsigned short*)node_in)[(size_t)ssrc[r] * 300 + q * 4];
        }
        for (int idx = tid; idx < 64 * (KP - 300); idx += 512) {
            int r = idx / (KP - 300), k = idx - r * (KP - 300);
            int kk = 300 + k;
            float v = (kk < K) ? ea[(size_t)(e0 + r) * 14 + (kk - 300)] : 0.f;
            As[r * LDK + kk] = f2bf_us(v);
        }
    } else {
        for (int idx = tid; idx < 64 * KP; idx += 512) {
            int r = idx / KP, k = idx - r * KP;
            float v;
            if (k < NID)    v = ld1(&node_in[(size_t)ssrc[r] * NID + k]);
            else if (k < K) v = ea[(size_t)(e0 + r) * 14 + (k - NID)];
            else            v = 0.f;
            As[r * LDK + k] = f2bf_us(v);
        }
    }
    __syncthreads();
    f32x4v acc[4][3];
    #pragma unroll
    for (int c = 0; c < 3; ++c) {
        int ct = wv + 8 * c;
        float b = 0.f;
        if (ct < 19) { int col = ct * 16 + cr; if (col < 300) b = bias[col]; }
        #pragma unroll
        for (int rt = 0; rt < 4; ++rt) { f32x4v a = {b, b, b, b}; acc[rt][c] = a; }
    }
    for (int kt = 0; kt < NKT; ++kt) {
        bf16x8v bhi[3], blo[3];
        #pragma unroll
        for (int c = 0; c < 3; ++c) {
            int ct = wv + 8 * c;
            if (ct < 19) {
                size_t base = ((size_t)(kt * 19 + ct) * 64 + lane) * 8;
                bhi[c] = *(const bf16x8v*)&whi[base];
                blo[c] = *(const bf16x8v*)&wlo[base];
            }
        }
        #pragma unroll
        for (int rt = 0; rt < 4; ++rt) {
            bf16x8v a = *(const bf16x8v*)&As[(rt * 16 + cr) * LDK + kt * 32 + quad * 8];
            #pragma unroll
            for (int c = 0; c < 3; ++c) {
                int ct = wv + 8 * c;
                if (ct >= 19) break;
                acc[rt][c] = __builtin_amdgcn_mfma_f32_16x16x32_bf16(a, blo[c], acc[rt][c], 0, 0, 0);
                acc[rt][c] = __builtin_amdgcn_mfma_f32_16x16x32_bf16(a, bhi[c], acc[rt][c], 0, 0, 0);
            }
        }
    }
    __syncthreads();
    #pragma unroll
    for (int c = 0; c < 3; ++c) {
        int ct = wv + 8 * c;
        if (ct >= 19) break;
        int col = ct * 16 + cr;
        if (col >= 300) continue;
        #pragma unroll
        for (int rt = 0; rt < 4; ++rt)
            #pragma unroll
            for (int r = 0; r < 4; ++r)
                As[(rt * 16 + quad * 4 + r) * LDK + col] = f2bf_us(fmaxf(acc[rt][c][r], 0.f));
    }
    __syncthreads();
    for (int idx = tid; idx < 64 * 75; idx += 512) {
        int r = idx / 75, q = idx - r * 75;
        *(ushort4*)&h[(size_t)(e0 + r) * 300 + q * 4] = *(const ushort4*)&As[r * LDK + q * 4];
    }
}

// ---------------- au GEMM (segsum FUSED): out[n] = (relu?)(concat(node_in[n], segsum_h[n]) @ W + b) ----
template <int NID, typename TN, bool RELU>
__global__ __launch_bounds__(512, 4) void k_au_mfma(
        const TN* __restrict__ node_in, const unsigned short* __restrict__ h,
        const int* __restrict__ elist, const int* __restrict__ start,
        const unsigned short* __restrict__ whi, const unsigned short* __restrict__ wlo,
        const float* __restrict__ bias, unsigned short* __restrict__ out_rows) {
    constexpr int K = NID + 300;
    constexpr int KP = (K + 31) & ~31;     // 448 or 608
    constexpr int NKT = KP / 32;
    constexpr int LDK = KP + 8;            // 456 / 616
    __shared__ unsigned short As[64 * LDK];
    const int tid = threadIdx.x;
    const int lane = tid & 63, wv = tid >> 6;
    const int quad = lane >> 4, cr = lane & 15;
    const int n0 = blockIdx.x * 64;
    // node part: cols [0, NID)
    if constexpr (NID == 300) {
        for (int idx = tid; idx < 64 * 75; idx += 512) {
            int r = idx / 75, q = idx - r * 75;
            *(ushort4*)&As[r * LDK + q * 4] =
                *(const ushort4*)&((const unsigned short*)node_in)[(size_t)(n0 + r) * 300 + q * 4];
        }
    } else {
        // contiguous 64-row fp32 block: flat aligned float4 copy (64*NID divisible by 4 for NID=133)
        const float* xb = (const float*)node_in + (size_t)n0 * NID;
        for (int f4 = tid; f4 < (64 * NID) / 4; f4 += 512) {
            float4 v = *(const float4*)&xb[f4 * 4];
            int f = f4 * 4;
            float vv[4] = {v.x, v.y, v.z, v.w};
            #pragma unroll
            for (int i = 0; i < 4; ++i) {
                int fi = f + i;
                int r = fi / NID, k = fi - r * NID;
                As[r * LDK + k] = f2bf_us(vv[i]);
            }
        }
    }
    // fused segment-sum gather (2-way unrolled): cols [NID, NID+300)
    for (int idx = tid; idx < 64 * 75; idx += 512) {
        int r = idx / 75, q = idx - r * 75;
        int n = n0 + r;
        int lo = clampi(start[n], 0, NE), hi = clampi(start[n + 1], 0, NE);
        float4 acc = make_float4(0.f, 0.f, 0.f, 0.f);
        int j = lo;
        for (; j + 2 <= hi; j += 2) {
            int ei0 = clampi(elist[j], 0, NE - 1);
            int ei1 = clampi(elist[j + 1], 0, NE - 1);
            float4 v0 = ld4(&h[(size_t)ei0 * 300 + q * 4]);
            float4 v1 = ld4(&h[(size_t)ei1 * 300 + q * 4]);
            acc.x += v0.x; acc.y += v0.y; acc.z += v0.z; acc.w += v0.w;
            acc.x += v1.x; acc.y += v1.y; acc.z += v1.z; acc.w += v1.w;
        }
        if (j < hi) {
            int ei0 = clampi(elist[j], 0, NE - 1);
            float4 v0 = ld4(&h[(size_t)ei0 * 300 + q * 4]);
            acc.x += v0.x; acc.y += v0.y; acc.z += v0.z; acc.w += v0.w;
        }
        unsigned short* dst = &As[r * LDK + NID + q * 4];
        dst[0] = f2bf_us(acc.x); dst[1] = f2bf_us(acc.y);
        dst[2] = f2bf_us(acc.z); dst[3] = f2bf_us(acc.w);
    }
    // pad: cols [NID+300, KP)
    constexpr int PAD = KP - NID - 300;
    for (int idx = tid; idx < 64 * PAD; idx += 512) {
        int r = idx / PAD, k = idx - r * PAD;
        As[r * LDK + NID + 300 + k] = 0;
    }
    __syncthreads();
    f32x4v acc[4][3];
    #pragma unroll
    for (int c = 0; c < 3; ++c) {
        int ct = wv + 8 * c;
        float b = 0.f;
        if (ct < 19) { int col = ct * 16 + cr; if (col < 300) b = bias[col]; }
        #pragma unroll
        for (int rt = 0; rt < 4; ++rt) { f32x4v a = {b, b, b, b}; acc[rt][c] = a; }
    }
    for (int kt = 0; kt < NKT; ++kt) {
        bf16x8v bhi[3], blo[3];
        #pragma unroll
        for (int c = 0; c < 3; ++c) {
            int ct = wv + 8 * c;
            if (ct < 19) {
                size_t base = ((size_t)(kt * 19 + ct) * 64 + lane) * 8;
                bhi[c] = *(const bf16x8v*)&whi[base];
                blo[c] = *(const bf16x8v*)&wlo[base];
            }
        }
        #pragma unroll
        for (int rt = 0; rt < 4; ++rt) {
            bf16x8v a = *(const bf16x8v*)&As[(rt * 16 + cr) * LDK + kt * 32 + quad * 8];
            #pragma unroll
            for (int c = 0; c < 3; ++c) {
                int ct = wv + 8 * c;
                if (ct >= 19) break;
                acc[rt][c] = __builtin_amdgcn_mfma_f32_16x16x32_bf16(a, blo[c], acc[rt][c], 0, 0, 0);
                acc[rt][c] = __builtin_amdgcn_mfma_f32_16x16x32_bf16(a, bhi[c], acc[rt][c], 0, 0, 0);
            }
        }
    }
    __syncthreads();
    #pragma unroll
    for (int c = 0; c < 3; ++c) {
        int ct = wv + 8 * c;
        if (ct >= 19) break;
        int col = ct * 16 + cr;
        if (col >= 300) continue;
        #pragma unroll
        for (int rt = 0; rt < 4; ++rt)
            #pragma unroll
            for (int r = 0; r < 4; ++r) {
                float v = acc[rt][c][r];
                As[(rt * 16 + quad * 4 + r) * LDK + col] = f2bf_us(RELU ? fmaxf(v, 0.f) : v);
            }
    }
    __syncthreads();
    for (int idx = tid; idx < 64 * 75; idx += 512) {
        int r = idx / 75, q = idx - r * 75;
        *(ushort4*)&out_rows[(size_t)(n0 + r) * 300 + q * 4] = *(const ushort4*)&As[r * LDK + q * 4];
    }
}

// ---------------- mp GEMM: h[e] = relu(h[e] + (inc[src[e]] - h[rev(e)]) @ W + b) ----------------
// 64 rows = 32 pairs / block (pair r <-> r+32)
__global__ __launch_bounds__(512, 4) void k_mp_mfma(
        unsigned short* __restrict__ h, const unsigned short* __restrict__ inc,
        const int* __restrict__ srcH, const int* __restrict__ dstH,
        const unsigned short* __restrict__ whi, const unsigned short* __restrict__ wlo,
        const float* __restrict__ bias) {
    constexpr int LDK = 328;
    __shared__ unsigned short Hs[64 * LDK];
    __shared__ int ssrc[64];
    const int tid = threadIdx.x;
    const int lane = tid & 63, wv = tid >> 6;
    const int quad = lane >> 4, cr = lane & 15;
    const int p0 = blockIdx.x * 32;
    if (tid < 64) {
        int r = tid;
        int e = (r < 32) ? (p0 + r) : (p0 + r - 32 + HALF);
        int s = (e < HALF) ? srcH[e] : dstH[e - HALF];
        ssrc[r] = clampi(s, 0, NN - 1);
    }
    for (int idx = tid; idx < 64 * 82; idx += 512) {
        int r = idx / 82, q = idx - r * 82;
        int col = q * 4;
        ushort4 v = make_ushort4(0, 0, 0, 0);
        if (col < 300) {
            int e = (r < 32) ? (p0 + r) : (p0 + r - 32 + HALF);
            v = *(const ushort4*)&h[(size_t)e * 300 + col];
        }
        *(ushort4*)&Hs[r * LDK + col] = v;
    }
    __syncthreads();
    f32x4v acc[4][3];
    #pragma unroll
    for (int c = 0; c < 3; ++c) {
        int ct = wv + 8 * c;
        int col = ct * 16 + cr;
        bool ok = (ct < 19) && (col < 300);
        float b = ok ? bias[col] : 0.f;
        #pragma unroll
        for (int rt = 0; rt < 4; ++rt) {
            f32x4v a = {0.f, 0.f, 0.f, 0.f};
            if (ok) {
                #pragma unroll
                for (int r = 0; r < 4; ++r)
                    a[r] = bf2f_us(Hs[(rt * 16 + quad * 4 + r) * LDK + col]) + b;
            }
            acc[rt][c] = a;
        }
    }
    __syncthreads();
    for (int idx = tid; idx < 32 * 75; idx += 512) {
        int r = idx / 75, q = idx - r * 75;
        int col = q * 4;
        float4 a = ld4(&Hs[r * LDK + col]);
        float4 b = ld4(&Hs[(r + 32) * LDK + col]);
        float4 i1 = ld4(&inc[(size_t)ssrc[r] * 300 + col]);
        float4 i2 = ld4(&inc[(size_t)ssrc[r + 32] * 300 + col]);
        st4(&Hs[r * LDK + col],        make_float4(i1.x - b.x, i1.y - b.y, i1.z - b.z, i1.w - b.w));
        st4(&Hs[(r + 32) * LDK + col], make_float4(i2.x - a.x, i2.y - a.y, i2.z - a.z, i2.w - a.w));
    }
    __syncthreads();
    for (int kt = 0; kt < 10; ++kt) {
        bf16x8v bhi[3], blo[3];
        #pragma unroll
        for (int c = 0; c < 3; ++c) {
            int ct = wv + 8 * c;
            if (ct < 19) {
                size_t base = ((size_t)(kt * 19 + ct) * 64 + lane) * 8;
                bhi[c] = *(const bf16x8v*)&whi[base];
                blo[c] = *(const bf16x8v*)&wlo[base];
            }
        }
        #pragma unroll
        for (int rt = 0; rt < 4; ++rt) {
            bf16x8v a = *(const bf16x8v*)&Hs[(rt * 16 + cr) * LDK + kt * 32 + quad * 8];
            #pragma unroll
            for (int c = 0; c < 3; ++c) {
                int ct = wv + 8 * c;
                if (ct >= 19) break;
                acc[rt][c] = __builtin_amdgcn_mfma_f32_16x16x32_bf16(a, blo[c], acc[rt][c], 0, 0, 0);
                acc[rt][c] = __builtin_amdgcn_mfma_f32_16x16x32_bf16(a, bhi[c], acc[rt][c], 0, 0, 0);
            }
        }
    }
    __syncthreads();
    #pragma unroll
    for (int c = 0; c < 3; ++c) {
        int ct = wv + 8 * c;
        if (ct >= 19) break;
        int col = ct * 16 + cr;
        if (col >= 300) continue;
        #pragma unroll
        for (int rt = 0; rt < 4; ++rt)
            #pragma unroll
            for (int r = 0; r < 4; ++r)
                Hs[(rt * 16 + quad * 4 + r) * LDK + col] = f2bf_us(fmaxf(acc[rt][c][r], 0.f));
    }
    __syncthreads();
    for (int idx = tid; idx < 64 * 75; idx += 512) {
        int r = idx / 75, q = idx - r * 75;
        int e = (r < 32) ? (p0 + r) : (p0 + r - 32 + HALF);
        *(ushort4*)&h[(size_t)e * 300 + q * 4] = *(const ushort4*)&Hs[r * LDK + q * 4];
    }
}

// ---------------- pooling (bf16 rows) + reparam ----------------
__global__ __launch_bounds__(320) void k_pool(const unsigned short* __restrict__ rows,
                                              const float* __restrict__ wat,
                                              const int* __restrict__ gs, float* __restrict__ outg) {
    int g = blockIdx.x, c = threadIdx.x;
    if (c >= 300) return;
    int lo = clampi(gs[g], 0, NN), hi = clampi(gs[g + 1], 0, NN);
    float acc = 0.f;
    for (int n = lo; n < hi; ++n)
        acc += bf2f_us(rows[(size_t)n * 300 + c]) * wat[n];
    float cn = fmaxf((float)(hi - lo), 1.f);
    outg[g * 300 + c] = acc / cn;
}
__global__ __launch_bounds__(320) void k_final(const float* __restrict__ mu_g, const float* __restrict__ lv_g,
                                               const float* __restrict__ eps, float* __restrict__ out) {
    int g = blockIdx.x, c = threadIdx.x;
    if (c >= 300) return;
    out[g * 300 + c] = mu_g[g * 300 + c] + expf(0.5f * lv_g[g * 300 + c]) * eps[g * 300 + c];
}

extern "C" void kernel_launch(void* const* d_in, const int* in_sizes, int n_in,
                              void* d_out, int out_size, void* d_ws, size_t ws_size,
                              hipStream_t stream) {
    float* outp = (float*)d_out;

    const size_t NEED = 199500000ull;   // carve ~199.43 MB; ws proven >= 200,000,000
    if (ws_size < NEED) {
        k_zerof<<<(out_size + 255) / 256, 256, 0, stream>>>(outp, out_size);
        return;
    }

    const float* x   = (const float*)d_in[0];
    const float* ea  = (const float*)d_in[1];
    const float* wat = (const float*)d_in[2];
    const float* eps = (const float*)d_in[3];
    const int* srcH  = (const int*)d_in[4];
    const int* dstH  = (const int*)d_in[5];
    const int* batch = (const int*)d_in[6];
    const float* w_t_lin  = (const float*)d_in[7];
    const float* b_t_lin  = (const float*)d_in[8];
    const float* w_t_mp   = (const float*)d_in[9];
    const float* b_t_mp   = (const float*)d_in[10];
    const float* w_t_au   = (const float*)d_in[11];
    const float* b_t_au   = (const float*)d_in[12];
    const float* w_mu_lin = (const float*)d_in[13];
    const float* b_mu_lin = (const float*)d_in[14];
    const float* w_mu_mp  = (const float*)d_in[15];
    const float* b_mu_mp  = (const float*)d_in[16];
    const float* w_mu_au  = (const float*)d_in[17];
    const float* b_mu_au  = (const float*)d_in[18];
    const float* w_lv_lin = (const float*)d_in[19];
    const float* b_lv_lin = (const float*)d_in[20];
    const float* w_lv_mp  = (const float*)d_in[21];
    const float* b_lv_mp  = (const float*)d_in[22];
    const float* w_lv_au  = (const float*)d_in[23];
    const float* b_lv_au  = (const float*)d_in[24];

    char* p = (char*)d_ws;
    auto alloc = [&](size_t nbytes) { char* q = p; p += (nbytes + 255) & ~(size_t)255; return q; };
    unsigned short* h   = (unsigned short*)alloc((size_t)NE * 300 * 2);   // 96 MB
    unsigned short* inc = (unsigned short*)alloc((size_t)NN * 300 * 2);   // 48 MB; dead during au -> reused as rows
    unsigned short* sh  = (unsigned short*)alloc((size_t)NN * 300 * 2);   // 48 MB
    const size_t MPU = (size_t)3 * 10 * 19 * 512;   // mp tables (ushorts)
    unsigned short* wh_mp = (unsigned short*)alloc(MPU * 2);
    unsigned short* wl_mp = (unsigned short*)alloc(MPU * 2);
    const size_t LAU = (size_t)29 * 19 * 512;       // lin+au tables
    unsigned short* wh_la = (unsigned short*)alloc(LAU * 2);
    unsigned short* wl_la = (unsigned short*)alloc(LAU * 2);
    float* mu_g = (float*)alloc((size_t)NG * 300 * 4);
    float* lv_g = (float*)alloc((size_t)NG * 300 * 4);
    int* deg    = (int*)alloc(NN * 4);               // reused as cursor (alias-safe)
    int* startA = (int*)alloc((NN + 1) * 4);
    int* elist  = (int*)alloc(NE * 4);
    int* degg   = (int*)alloc(NG * 4);
    int* gs     = (int*)alloc((NG + 1) * 4);
    int* part   = (int*)alloc(SCB * 4);

    // ---- CSR (incoming by dst), multi-block scan; cursor aliases deg ----
    k_zeroi<<<(NN + 255) / 256, 256, 0, stream>>>(deg, NN);
    k_hist<<<(NE + 255) / 256, 256, 0, stream>>>(srcH, dstH, deg);
    k_scan_part<<<SCB, 256, 0, stream>>>(deg, part, NN);
    k_scan_offsets<<<1, 256, 0, stream>>>(part);
    k_scan_apply<<<SCB, 256, 0, stream>>>(deg, part, startA, deg, NN);
    k_fill<<<(NE + 255) / 256, 256, 0, stream>>>(srcH, dstH, deg, elist);
    // ---- graph-CSR over sorted batch ----
    k_zeroi<<<(NG + 255) / 256, 256, 0, stream>>>(degg, NG);
    k_histg<<<(NN + 255) / 256, 256, 0, stream>>>(batch, degg);
    k_scan_part<<<SCB, 256, 0, stream>>>(degg, part, NG);
    k_scan_offsets<<<1, 256, 0, stream>>>(part);
    k_scan_apply<<<SCB, 256, 0, stream>>>(degg, part, gs, (int*)nullptr, NG);

    const int SSG = (NN * 75 + 255) / 256;
    const size_t MP_L = (size_t)10 * 19 * 512;      // ushorts per mp layer
    unsigned short* rows = inc;                      // au output aliases inc (dead during au)
    auto wsplit_conv = [&](const float* Wmp, const float* Wlin, int Klin, int nktlin,
                           const float* Wau, int Kau, int nktau) {
        int total = 570 + nktlin * 19 + nktau * 19;
        k_wsplit_conv<<<(total * 64 + 255) / 256, 256, 0, stream>>>(
            Wmp, Wlin, Klin, nktlin, Wau, Kau, nktau, wh_mp, wl_mp, wh_la, wl_la);
    };

    // ================= conv t =================
    wsplit_conv(w_t_mp, w_t_lin, 147, 5, w_t_au, 433, 14);
    const size_t AU_T = (size_t)5 * 19 * 512;
    k_lin_mfma<133, float><<<NE / 64, 512, 0, stream>>>(x, ea, srcH, dstH, wh_la, wl_la, b_t_lin, h);
    for (int i = 0; i < 3; ++i) {
        k_segsum2<<<SSG, 256, 0, stream>>>(h, elist, startA, inc);
        k_mp_mfma<<<HALF / 32, 512, 0, stream>>>(h, inc, srcH, dstH,
                                                 wh_mp + i * MP_L, wl_mp + i * MP_L, b_t_mp + i * 300);
    }
    k_au_mfma<133, float, true><<<NN / 64, 512, 0, stream>>>(x, h, elist, startA,
                                                             wh_la + AU_T, wl_la + AU_T, b_t_au, sh);

    // ================= conv mu =================
    wsplit_conv(w_mu_mp, w_mu_lin, 314, 10, w_mu_au, 600, 19);
    const size_t AU_MU = (size_t)10 * 19 * 512;
    k_lin_mfma<300, unsigned short><<<NE / 64, 512, 0, stream>>>(sh, ea, srcH, dstH, wh_la, wl_la, b_mu_lin, h);
    for (int i = 0; i < 3; ++i) {
        k_segsum2<<<SSG, 256, 0, stream>>>(h, elist, startA, inc);
        k_mp_mfma<<<HALF / 32, 512, 0, stream>>>(h, inc, srcH, dstH,
                                                 wh_mp + i * MP_L, wl_mp + i * MP_L, b_mu_mp + i * 300);
    }
    k_au_mfma<300, unsigned short, false><<<NN / 64, 512, 0, stream>>>(sh, h, elist, startA,
                                                                       wh_la + AU_MU, wl_la + AU_MU, b_mu_au, rows);
    k_pool<<<NG, 320, 0, stream>>>(rows, wat, gs, mu_g);

    // ================= conv lv =================
    wsplit_conv(w_lv_mp, w_lv_lin, 314, 10, w_lv_au, 600, 19);
    k_lin_mfma<300, unsigned short><<<NE / 64, 512, 0, stream>>>(sh, ea, srcH, dstH, wh_la, wl_la, b_lv_lin, h);
    for (int i = 0; i < 3; ++i) {
        k_segsum2<<<SSG, 256, 0, stream>>>(h, elist, startA, inc);
        k_mp_mfma<<<HALF / 32, 512, 0, stream>>>(h, inc, srcH, dstH,
                                                 wh_mp + i * MP_L, wl_mp + i * MP_L, b_lv_mp + i * 300);
    }
    k_au_mfma<300, unsigned short, false><<<NN / 64, 512, 0, stream>>>(sh, h, elist, startA,
                                                                       wh_la + AU_MU, wl_la + AU_MU, b_lv_au, rows);
    k_pool<<<NG, 320, 0, stream>>>(rows, wat, gs, lv_g);

    // ---- reparam ----
    k_final<<<NG, 320, 0, stream>>>(mu_g, lv_g, eps, outp);
}